// Round 1
// baseline (1907.786 us; speedup 1.0000x reference)
//
#include <hip/hip_runtime.h>
#include <math.h>

#define BB 8
#define HH 32
#define WW 32
#define LL 1024
#define CC 256

// ---------------------------------------------------------------------------
// Small kernels
// ---------------------------------------------------------------------------

// norms[b,l] = max(sqrt(G[b,l,l]), 1e-4); mm[b,l] from mask patches; ones output
__global__ __launch_bounds__(256) void norm_mm_ones_kernel(
    const float* __restrict__ G, const float* __restrict__ mask,
    float* __restrict__ norms, float* __restrict__ mm, float* __restrict__ ones_out) {
  int idx = blockIdx.x * 256 + threadIdx.x;  // 0..8191
  int b = idx >> 10, l = idx & 1023;
  float d = G[((size_t)b << 20) + (size_t)l * LL + l];
  norms[idx] = fmaxf(sqrtf(d), 1e-4f);
  int lh = l >> 5, lw = l & 31;
  float s = 0.f;
  for (int dh = -1; dh <= 1; ++dh)
    for (int dw = -1; dw <= 1; ++dw) {
      int hh = lh + dh, wv = lw + dw;
      if (hh >= 0 && hh < HH && wv >= 0 && wv < WW)
        s += mask[b * LL + hh * WW + wv];
    }
  mm[idx] = ((s / 9.0f) == 1.0f) ? 1.0f : 0.0f;
  ones_out[idx] = 1.0f;
}

// G[b,i,j] /= norms[b,j]  (column-wise normalization), in place
__global__ __launch_bounds__(256) void normalize_kernel(
    float* __restrict__ G, const float* __restrict__ norms) {
  size_t idx = ((size_t)blockIdx.x * 256 + threadIdx.x) * 4;  // 8M elems total
  int b = (int)(idx >> 20);
  int j = (int)(idx & 1023);
  const float4 nv = *(const float4*)(norms + (b << 10) + j);
  float4 v = *(float4*)(G + idx);
  v.x /= nv.x; v.y /= nv.y; v.z /= nv.z; v.w /= nv.w;
  *(float4*)(G + idx) = v;
}

// ---------------------------------------------------------------------------
// Fused diag-fuse + mask + softmax: reads normalized Y, writes A
// ---------------------------------------------------------------------------

__device__ __forceinline__ int sigm(int m) { return ((m & 31) << 5) | (m >> 5); }

__device__ __forceinline__ float z1read(const float* __restrict__ Yb, int r, int s) {
  float v = Yb[(size_t)r * LL + s];
  if (r >= 1 && s >= 1)           v += Yb[(size_t)(r - 1) * LL + (s - 1)];
  if (r <= LL - 2 && s <= LL - 2) v += Yb[(size_t)(r + 1) * LL + (s + 1)];
  return v;
}

__global__ __launch_bounds__(256) void fuse_softmax_kernel(
    const float* __restrict__ Yn, const float* __restrict__ mm, float* __restrict__ Aout) {
  int bi = blockIdx.x;  // 0..8191  (b, row i)
  int b = bi >> 10, i = bi & 1023;
  const float* Yb = Yn + ((size_t)b << 20);
  const float* mmb = mm + (b << 10);
  float* Arow = Aout + ((size_t)b << 20) + (size_t)i * LL;
  int si = sigm(i);
  int rm = (si >= 1) ? sigm(si - 1) : -1;
  int rp = (si <= LL - 2) ? sigm(si + 1) : -1;
  int tid = threadIdx.x;
  float logit[4];
  float lmax = -3.0e38f;
#pragma unroll
  for (int q = 0; q < 4; ++q) {
    int j = tid + (q << 8);
    int sj = sigm(j);
    float S = z1read(Yb, i, j);
    if (rm >= 0 && sj >= 1)      S += z1read(Yb, rm, sigm(sj - 1));
    if (rp >= 0 && sj <= LL - 2) S += z1read(Yb, rp, sigm(sj + 1));
    float lg = S * mmb[j] * 10.0f;  // masked columns contribute logit 0 (not -inf)
    logit[q] = lg;
    lmax = fmaxf(lmax, lg);
  }
  __shared__ float red[256];
  red[tid] = lmax; __syncthreads();
  for (int off = 128; off > 0; off >>= 1) {
    if (tid < off) red[tid] = fmaxf(red[tid], red[tid + off]);
    __syncthreads();
  }
  float M = red[0];
  __syncthreads();
  float ex[4];
  float lsum = 0.f;
#pragma unroll
  for (int q = 0; q < 4; ++q) { ex[q] = expf(logit[q] - M); lsum += ex[q]; }
  red[tid] = lsum; __syncthreads();
  for (int off = 128; off > 0; off >>= 1) {
    if (tid < off) red[tid] += red[tid + off];
    __syncthreads();
  }
  float inv = 1.0f / red[0];
#pragma unroll
  for (int q = 0; q < 4; ++q) {
    int j = tid + (q << 8);
    Arow[j] = mmb[j] * ex[q] * inv;
  }
}

// ---------------------------------------------------------------------------
// GEMM 1: Gram  G[b,p,l] = sum_{delta,c} xpad[p+d]*xpad[l+d]
// ---------------------------------------------------------------------------

__global__ __launch_bounds__(256) void gram_kernel(
    const float* __restrict__ x, float* __restrict__ G) {
  const int b = blockIdx.z;
  const int m0 = blockIdx.x << 6;
  const int n0 = blockIdx.y << 6;
  const float* xb = x + ((size_t)b << 18);
  __shared__ float As[16][68];
  __shared__ float Bs[16][68];
  const int tid = threadIdx.x;
  const int tm4 = (tid >> 4) << 2;
  const int tn4 = (tid & 15) << 2;
  const int lr = tid >> 2;
  const int lc = (tid & 3) << 2;
  float acc[4][4] = {{0.f}};
  for (int s = 0; s < 9; ++s) {
    const int dh = s / 3 - 1, dw = s % 3 - 1;
    int pa = m0 + lr;
    int pah = (pa >> 5) + dh, paw = (pa & 31) + dw;
    bool va = (pah >= 0) && (pah < HH) && (paw >= 0) && (paw < WW);
    const float* arow = xb + (size_t)(va ? (pah * WW + paw) : 0) * CC;
    int pb = n0 + lr;
    int pbh = (pb >> 5) + dh, pbw = (pb & 31) + dw;
    bool vb = (pbh >= 0) && (pbh < HH) && (pbw >= 0) && (pbw < WW);
    const float* brow = xb + (size_t)(vb ? (pbh * WW + pbw) : 0) * CC;
    for (int c0 = 0; c0 < CC; c0 += 16) {
      __syncthreads();
      float4 av = va ? *(const float4*)(arow + c0 + lc) : make_float4(0.f, 0.f, 0.f, 0.f);
      float4 bv = vb ? *(const float4*)(brow + c0 + lc) : make_float4(0.f, 0.f, 0.f, 0.f);
      As[lc + 0][lr] = av.x; As[lc + 1][lr] = av.y; As[lc + 2][lr] = av.z; As[lc + 3][lr] = av.w;
      Bs[lc + 0][lr] = bv.x; Bs[lc + 1][lr] = bv.y; Bs[lc + 2][lr] = bv.z; Bs[lc + 3][lr] = bv.w;
      __syncthreads();
#pragma unroll
      for (int kk = 0; kk < 16; ++kk) {
        float a[4], bv2[4];
#pragma unroll
        for (int t = 0; t < 4; ++t) a[t] = As[kk][tm4 + t];
#pragma unroll
        for (int t = 0; t < 4; ++t) bv2[t] = Bs[kk][tn4 + t];
#pragma unroll
        for (int i2 = 0; i2 < 4; ++i2)
#pragma unroll
          for (int j2 = 0; j2 < 4; ++j2) acc[i2][j2] += a[i2] * bv2[j2];
      }
    }
  }
  float* gout = G + ((size_t)b << 20);
#pragma unroll
  for (int i2 = 0; i2 < 4; ++i2) {
    int row = m0 + tm4 + i2;
    float4 v = make_float4(acc[i2][0], acc[i2][1], acc[i2][2], acc[i2][3]);
    *(float4*)(gout + (size_t)row * LL + n0 + tn4) = v;
  }
}

// ---------------------------------------------------------------------------
// GEMM 2: paste  y[b,q,c] = sum_s sum_l A[b, q-d_s, l] * xpad[b, l+d_s, c]
// ---------------------------------------------------------------------------

__global__ __launch_bounds__(256) void paste_kernel(
    const float* __restrict__ Amat, const float* __restrict__ x, float* __restrict__ y) {
  const int b = blockIdx.z;
  const int m0 = blockIdx.x << 6;   // q tile
  const int cb0 = blockIdx.y << 6;  // channel tile
  const float* Ab = Amat + ((size_t)b << 20);
  const float* xb = x + ((size_t)b << 18);
  __shared__ float As[16][68];
  __shared__ float Bs[16][68];
  const int tid = threadIdx.x;
  const int tm4 = (tid >> 4) << 2, tn4 = (tid & 15) << 2;
  const int lr = tid >> 2, lc = (tid & 3) << 2;
  const int bk = tid >> 4, bco = (tid & 15) << 2;
  float acc[4][4] = {{0.f}};
  for (int s = 0; s < 9; ++s) {
    const int dh = s / 3 - 1, dw = s % 3 - 1;
    int q = m0 + lr;
    int qh = (q >> 5) - dh, qw = (q & 31) - dw;
    bool va = (qh >= 0) && (qh < HH) && (qw >= 0) && (qw < WW);
    const float* arow = Ab + (size_t)(va ? (qh * WW + qw) : 0) * LL;
    for (int l0 = 0; l0 < LL; l0 += 16) {
      int pl = l0 + bk;
      int plh = (pl >> 5) + dh, plw = (pl & 31) + dw;
      bool vb = (plh >= 0) && (plh < HH) && (plw >= 0) && (plw < WW);
      const float* brow = xb + (size_t)(vb ? (plh * WW + plw) : 0) * CC;
      __syncthreads();
      float4 av = va ? *(const float4*)(arow + l0 + lc) : make_float4(0.f, 0.f, 0.f, 0.f);
      As[lc + 0][lr] = av.x; As[lc + 1][lr] = av.y; As[lc + 2][lr] = av.z; As[lc + 3][lr] = av.w;
      float4 bv = vb ? *(const float4*)(brow + cb0 + bco) : make_float4(0.f, 0.f, 0.f, 0.f);
      Bs[bk][bco + 0] = bv.x; Bs[bk][bco + 1] = bv.y; Bs[bk][bco + 2] = bv.z; Bs[bk][bco + 3] = bv.w;
      __syncthreads();
#pragma unroll
      for (int kk = 0; kk < 16; ++kk) {
        float a[4], bv2[4];
#pragma unroll
        for (int t = 0; t < 4; ++t) a[t] = As[kk][tm4 + t];
#pragma unroll
        for (int t = 0; t < 4; ++t) bv2[t] = Bs[kk][tn4 + t];
#pragma unroll
        for (int i2 = 0; i2 < 4; ++i2)
#pragma unroll
          for (int j2 = 0; j2 < 4; ++j2) acc[i2][j2] += a[i2] * bv2[j2];
      }
    }
  }
  float* yb = y + ((size_t)b << 18);
#pragma unroll
  for (int i2 = 0; i2 < 4; ++i2) {
    float4 v = make_float4(acc[i2][0], acc[i2][1], acc[i2][2], acc[i2][3]);
    *(float4*)(yb + (size_t)(m0 + tm4 + i2) * CC + cb0 + tn4) = v;
  }
}

// ---------------------------------------------------------------------------
// GEMM 3: fused final convs + gating
// out[m,co] = 0.5*(sig(c1+b1)+sig(c2+b2)) * (c0+b0)
// c0/c2: 3x3x512 convs of ycat=[y|x]; c1: 1x1x512 (center tap)
// ---------------------------------------------------------------------------

__global__ __launch_bounds__(256) void final_kernel(
    const float* __restrict__ y, const float* __restrict__ x,
    const float* __restrict__ w0, const float* __restrict__ bias0,
    const float* __restrict__ w1, const float* __restrict__ bias1,
    const float* __restrict__ w2, const float* __restrict__ bias2,
    float* __restrict__ out) {
  const int m0 = blockIdx.x << 6;  // 0..8191 positions (b*1024+q)
  const int b = m0 >> 10;
  const int q0 = m0 & 1023;
  const int cb0 = blockIdx.y << 6;
  const float* yb = y + ((size_t)b << 18);
  const float* xb = x + ((size_t)b << 18);
  __shared__ float As[16][68];
  __shared__ float B0s[16][68];
  __shared__ float B2s[16][68];
  __shared__ float B1s[16][68];
  const int tid = threadIdx.x;
  const int tm4 = (tid >> 4) << 2, tn4 = (tid & 15) << 2;
  const int lr = tid >> 2, lc = (tid & 3) << 2;
  const int bk = tid >> 4, bco = (tid & 15) << 2;
  float acc0[4][4] = {{0.f}}, acc1[4][4] = {{0.f}}, acc2[4][4] = {{0.f}};
  for (int s = 0; s < 9; ++s) {
    const int dh = s / 3 - 1, dw = s % 3 - 1;
    int q = q0 + lr;
    int qh2 = (q >> 5) + dh, qw2 = (q & 31) + dw;
    bool va = (qh2 >= 0) && (qh2 < HH) && (qw2 >= 0) && (qw2 < WW);
    int pidx = va ? (qh2 * WW + qw2) : 0;
    for (int c0i = 0; c0i < 512; c0i += 16) {
      __syncthreads();
      int cc = c0i + lc;
      const float* src = (cc < 256) ? (yb + (size_t)pidx * CC + cc)
                                    : (xb + (size_t)pidx * CC + (cc - 256));
      float4 av = va ? *(const float4*)src : make_float4(0.f, 0.f, 0.f, 0.f);
      As[lc + 0][lr] = av.x; As[lc + 1][lr] = av.y; As[lc + 2][lr] = av.z; As[lc + 3][lr] = av.w;
      size_t krow = (size_t)(s * 512 + c0i + bk) * 256 + cb0 + bco;
      float4 w0v = *(const float4*)(w0 + krow);
      B0s[bk][bco + 0] = w0v.x; B0s[bk][bco + 1] = w0v.y; B0s[bk][bco + 2] = w0v.z; B0s[bk][bco + 3] = w0v.w;
      float4 w2v = *(const float4*)(w2 + krow);
      B2s[bk][bco + 0] = w2v.x; B2s[bk][bco + 1] = w2v.y; B2s[bk][bco + 2] = w2v.z; B2s[bk][bco + 3] = w2v.w;
      if (s == 4) {
        float4 w1v = *(const float4*)(w1 + (size_t)(c0i + bk) * 256 + cb0 + bco);
        B1s[bk][bco + 0] = w1v.x; B1s[bk][bco + 1] = w1v.y; B1s[bk][bco + 2] = w1v.z; B1s[bk][bco + 3] = w1v.w;
      }
      __syncthreads();
      if (s == 4) {
#pragma unroll
        for (int kk = 0; kk < 16; ++kk) {
          float a[4], v0[4], v1[4], v2[4];
#pragma unroll
          for (int t = 0; t < 4; ++t) a[t] = As[kk][tm4 + t];
#pragma unroll
          for (int t = 0; t < 4; ++t) v0[t] = B0s[kk][tn4 + t];
#pragma unroll
          for (int t = 0; t < 4; ++t) v1[t] = B1s[kk][tn4 + t];
#pragma unroll
          for (int t = 0; t < 4; ++t) v2[t] = B2s[kk][tn4 + t];
#pragma unroll
          for (int i2 = 0; i2 < 4; ++i2)
#pragma unroll
            for (int j2 = 0; j2 < 4; ++j2) {
              acc0[i2][j2] += a[i2] * v0[j2];
              acc1[i2][j2] += a[i2] * v1[j2];
              acc2[i2][j2] += a[i2] * v2[j2];
            }
        }
      } else {
#pragma unroll
        for (int kk = 0; kk < 16; ++kk) {
          float a[4], v0[4], v2[4];
#pragma unroll
          for (int t = 0; t < 4; ++t) a[t] = As[kk][tm4 + t];
#pragma unroll
          for (int t = 0; t < 4; ++t) v0[t] = B0s[kk][tn4 + t];
#pragma unroll
          for (int t = 0; t < 4; ++t) v2[t] = B2s[kk][tn4 + t];
#pragma unroll
          for (int i2 = 0; i2 < 4; ++i2)
#pragma unroll
            for (int j2 = 0; j2 < 4; ++j2) {
              acc0[i2][j2] += a[i2] * v0[j2];
              acc2[i2][j2] += a[i2] * v2[j2];
            }
        }
      }
    }
  }
#pragma unroll
  for (int i2 = 0; i2 < 4; ++i2) {
    int m = m0 + tm4 + i2;
    float4 o;
#pragma unroll
    for (int j2 = 0; j2 < 4; ++j2) {
      int co = cb0 + tn4 + j2;
      float g1 = 1.f / (1.f + expf(-(acc1[i2][j2] + bias1[co])));
      float g2 = 1.f / (1.f + expf(-(acc2[i2][j2] + bias2[co])));
      float val = 0.5f * (g1 + g2) * (acc0[i2][j2] + bias0[co]);
      ((float*)&o)[j2] = val;
    }
    *(float4*)(out + (size_t)m * 256 + cb0 + tn4) = o;
  }
}

// ---------------------------------------------------------------------------

extern "C" void kernel_launch(void* const* d_in, const int* in_sizes, int n_in,
                              void* d_out, int out_size, void* d_ws, size_t ws_size,
                              hipStream_t stream) {
  const float* x = (const float*)d_in[0];
  const float* mask = (const float*)d_in[1];
  const float* conv_w = (const float*)d_in[2];
  const float* conv_b = (const float*)d_in[3];
  const float* conv1_w = (const float*)d_in[4];
  const float* conv1_b = (const float*)d_in[5];
  const float* conv2_w = (const float*)d_in[6];
  const float* conv2_b = (const float*)d_in[7];
  float* out = (float*)d_out;
  float* ws = (float*)d_ws;

  float* G = ws;                              // 8M floats  (scores / normalized Y)
  float* A = ws + ((size_t)8 << 20);          // 8M floats  (attention)
  float* norms = ws + ((size_t)16 << 20);     // 8192
  float* mmb = norms + 8192;                  // 8192
  float* yb = mmb + 8192;                     // 2M floats

  gram_kernel<<<dim3(16, 16, 8), 256, 0, stream>>>(x, G);
  norm_mm_ones_kernel<<<32, 256, 0, stream>>>(G, mask, norms, mmb,
                                              out + (size_t)BB * LL * CC);
  normalize_kernel<<<8192, 256, 0, stream>>>(G, norms);
  fuse_softmax_kernel<<<8192, 256, 0, stream>>>(G, mmb, A);
  paste_kernel<<<dim3(16, 4, 8), 256, 0, stream>>>(A, x, yb);
  final_kernel<<<dim3(128, 4), 256, 0, stream>>>(yb, x, conv_w, conv_b, conv1_w,
                                                 conv1_b, conv2_w, conv2_b, out);
}

// Round 2
// 442.497 us; speedup vs baseline: 4.3114x; 4.3114x over previous
//
#include <hip/hip_runtime.h>
#include <math.h>

typedef unsigned short u16;
typedef __bf16 bf16x8 __attribute__((ext_vector_type(8)));
typedef float f32x4 __attribute__((ext_vector_type(4)));

#define NPOS 1156          // 34*34 padded positions
#define S3STRIDE 2228224   // elements per w-shifted copy: 8*256*1088

__device__ __forceinline__ u16 f2bf(float f) {
  unsigned int u = __builtin_bit_cast(unsigned int, f);
  return (u16)((u + 0x7FFFu + ((u >> 16) & 1u)) >> 16);
}
__device__ __forceinline__ float bf2f(u16 v) {
  unsigned int u = ((unsigned int)v) << 16;
  return __builtin_bit_cast(float, u);
}
__device__ __forceinline__ void gload16(const void* g, void* l) {
  __builtin_amdgcn_global_load_lds(
      (const __attribute__((address_space(1))) void*)g,
      (__attribute__((address_space(3))) void*)l, 16, 0, 0);
}
__device__ __forceinline__ int posOf(int p) {  // interior padded position
  return ((p >> 5) + 1) * 34 + (p & 31) + 1;
}

// ---------------------------------------------------------------------------
// cast x -> xpad [b][34][34][256] bf16 (zero border via memset) and
// S_d (d=-1,0,1): [d][b*256+c][34][32] bf16, S_d[c][rr][lw] = x at padded pos
// (rr*34 + lw+1+d) for channel c. Border rows rr=0,33 stay zero (memset).
// ---------------------------------------------------------------------------
__global__ __launch_bounds__(256) void cast_x(
    const float* __restrict__ x, u16* __restrict__ xpad, u16* __restrict__ S3) {
  int blk = blockIdx.x;  // b*32 + h
  int b = blk >> 5, h = blk & 31;
  __shared__ u16 T[256][33];
  const float* xrow = x + ((size_t)b * 1024 + h * 32) * 256;
  int tid = threadIdx.x;
  for (int idx = tid; idx < 8192; idx += 256) {
    int w = idx >> 8, c = idx & 255;
    u16 v = f2bf(xrow[(size_t)w * 256 + c]);
    T[c][w] = v;
    xpad[((size_t)b * NPOS + (h + 1) * 34 + (w + 1)) * 256 + c] = v;
  }
  __syncthreads();
  int c = tid;
#pragma unroll
  for (int d = -1; d <= 1; ++d) {
    u16* Sd = S3 + (size_t)(d + 1) * S3STRIDE + ((size_t)(b * 256 + c)) * 1088 +
              (size_t)(h + 1) * 32;
    for (int w = 0; w < 32; ++w) {
      int ws2 = w + d;
      Sd[w] = (ws2 >= 0 && ws2 < 32) ? T[c][ws2] : (u16)0;
    }
  }
}

// weight transpose: src f32 [K][256] -> dst bf16 [256][K]
__global__ __launch_bounds__(256) void wtrans(
    const float* __restrict__ src, u16* __restrict__ dst, int K) {
  int k0 = blockIdx.x * 32;
  __shared__ u16 T[256][34];
  int tid = threadIdx.x;
  for (int idx = tid; idx < 8192; idx += 256) {
    int kr = idx >> 8, c = idx & 255;
    T[c][kr] = f2bf(src[(size_t)(k0 + kr) * 256 + c]);
  }
  __syncthreads();
  int c = tid;
  unsigned int* dp = (unsigned int*)(dst + (size_t)c * K + k0);
  const unsigned int* sp = (const unsigned int*)&T[c][0];
#pragma unroll
  for (int u = 0; u < 16; ++u) dp[u] = sp[u];
}

// ---------------------------------------------------------------------------
// Gram MFMA: G[b,p,l] (bf16) = sum_{s,c} xpad[p+ds][c]*xpad[l+ds][c]
// 128x128 tile, BK=64, 4 waves (64x64 each, 4x4 16x16x32 frags)
// ---------------------------------------------------------------------------
__global__ __launch_bounds__(256) void gram_mfma(
    const u16* __restrict__ xpad, u16* __restrict__ G) {
  const int b = blockIdx.z;
  const int m0 = blockIdx.x << 7;
  const int n0 = blockIdx.y << 7;
  const u16* xb = xpad + (size_t)b * NPOS * 256;
  __shared__ __align__(16) u16 As[128 * 64];
  __shared__ __align__(16) u16 Bs[128 * 64];
  const int tid = threadIdx.x;
  const int lane = tid & 63;
  const int wave = tid >> 6;
  const int wm = wave >> 1, wn = wave & 1;
  const int srow = lane >> 3;
  const int cswz = ((lane & 7) ^ srow) << 3;
  int pa[4], pb[4];
#pragma unroll
  for (int i = 0; i < 4; ++i) {
    pa[i] = posOf(m0 + wave * 32 + i * 8 + srow);
    pb[i] = posOf(n0 + wave * 32 + i * 8 + srow);
  }
  int aidx[4][2], bidx[4][2];
#pragma unroll
  for (int f = 0; f < 4; ++f)
#pragma unroll
    for (int ks = 0; ks < 2; ++ks) {
      int ra = wm * 64 + f * 16 + (lane & 15);
      int rb = wn * 64 + f * 16 + (lane & 15);
      int k16 = ks * 4 + (lane >> 4);
      aidx[f][ks] = ra * 64 + ((k16 ^ (ra & 7)) << 3);
      bidx[f][ks] = rb * 64 + ((k16 ^ (rb & 7)) << 3);
    }
  f32x4 acc[4][4] = {};
  for (int s = 0; s < 9; ++s) {
    const int dpos = (s / 3 - 1) * 34 + (s % 3 - 1);
    for (int c0 = 0; c0 < 256; c0 += 64) {
      __syncthreads();
#pragma unroll
      for (int i = 0; i < 4; ++i) {
        gload16(xb + (size_t)(pa[i] + dpos) * 256 + c0 + cswz, &As[(wave * 32 + i * 8) * 64]);
        gload16(xb + (size_t)(pb[i] + dpos) * 256 + c0 + cswz, &Bs[(wave * 32 + i * 8) * 64]);
      }
      __syncthreads();
#pragma unroll
      for (int ks = 0; ks < 2; ++ks) {
        bf16x8 a[4], bb[4];
#pragma unroll
        for (int f = 0; f < 4; ++f) a[f] = *(const bf16x8*)(As + aidx[f][ks]);
#pragma unroll
        for (int f = 0; f < 4; ++f) bb[f] = *(const bf16x8*)(Bs + bidx[f][ks]);
#pragma unroll
        for (int mi = 0; mi < 4; ++mi)
#pragma unroll
          for (int ni = 0; ni < 4; ++ni)
            acc[mi][ni] = __builtin_amdgcn_mfma_f32_16x16x32_bf16(a[mi], bb[ni], acc[mi][ni], 0, 0, 0);
      }
    }
  }
  u16* Gb = G + ((size_t)b << 20);
  const int r0 = (lane >> 4) << 2;
  const int cb0 = n0 + wn * 64 + (lane & 15);
#pragma unroll
  for (int mi = 0; mi < 4; ++mi) {
    int row = m0 + wm * 64 + mi * 16 + r0;
#pragma unroll
    for (int ni = 0; ni < 4; ++ni) {
      int col = cb0 + ni * 16;
#pragma unroll
      for (int r = 0; r < 4; ++r)
        Gb[(size_t)(row + r) * 1024 + col] = f2bf(acc[mi][ni][r]);
    }
  }
}

// invn, mm, ones tail
__global__ __launch_bounds__(256) void norm_mm(
    const u16* __restrict__ G, const float* __restrict__ mask,
    float* __restrict__ invn, float* __restrict__ mm, float* __restrict__ ones_out) {
  int idx = blockIdx.x * 256 + threadIdx.x;
  int b = idx >> 10, l = idx & 1023;
  float d = bf2f(G[((size_t)b << 20) + (size_t)l * 1025]);
  invn[idx] = 1.0f / fmaxf(sqrtf(d), 1e-4f);
  int lh = l >> 5, lw = l & 31;
  float s = 0.f;
  for (int dh = -1; dh <= 1; ++dh)
    for (int dw = -1; dw <= 1; ++dw) {
      int hh = lh + dh, wv = lw + dw;
      if (hh >= 0 && hh < 32 && wv >= 0 && wv < 32) s += mask[b * 1024 + hh * 32 + wv];
    }
  mm[idx] = ((s / 9.0f) == 1.0f) ? 1.0f : 0.0f;
  ones_out[idx] = 1.0f;
}

// ---------------------------------------------------------------------------
// Fused diag-fuse + mask + softmax -> Apad (bf16, padded rows)
// ---------------------------------------------------------------------------
__device__ __forceinline__ float z1f(const u16* __restrict__ Yb,
                                     const float* __restrict__ sinv, int r, int s2) {
  float v = bf2f(Yb[(size_t)r * 1024 + s2]) * sinv[s2];
  if (r >= 1 && s2 >= 1) v += bf2f(Yb[(size_t)(r - 1) * 1024 + (s2 - 1)]) * sinv[s2 - 1];
  if (r <= 1022 && s2 <= 1022) v += bf2f(Yb[(size_t)(r + 1) * 1024 + (s2 + 1)]) * sinv[s2 + 1];
  return v;
}

__global__ __launch_bounds__(256) void fuse_softmax(
    const u16* __restrict__ G, const float* __restrict__ invn,
    const float* __restrict__ mm, u16* __restrict__ Apad) {
  const int bi = blockIdx.x;
  const int b = bi >> 10, i = bi & 1023;
  const u16* Yb = G + ((size_t)b << 20);
  __shared__ float sinv[1024];
  __shared__ float smm[1024];
  __shared__ float red[256];
  const int tid = threadIdx.x;
  for (int t = tid; t < 1024; t += 256) {
    sinv[t] = invn[(b << 10) + t];
    smm[t] = mm[(b << 10) + t];
  }
  __syncthreads();
  const int si = ((i & 31) << 5) | (i >> 5);
  const int rm = (si >= 1) ? ((((si - 1) & 31) << 5) | ((si - 1) >> 5)) : -1;
  const int rp = (si <= 1022) ? ((((si + 1) & 31) << 5) | ((si + 1) >> 5)) : -1;
  float logit[4];
  float lmax = -3.0e38f;
#pragma unroll
  for (int q = 0; q < 4; ++q) {
    int j = tid + (q << 8);
    int sj = ((j & 31) << 5) | (j >> 5);
    float S = z1f(Yb, sinv, i, j);
    if (rm >= 0 && sj >= 1) {
      int col = (((sj - 1) & 31) << 5) | ((sj - 1) >> 5);
      S += z1f(Yb, sinv, rm, col);
    }
    if (rp >= 0 && sj <= 1022) {
      int col = (((sj + 1) & 31) << 5) | ((sj + 1) >> 5);
      S += z1f(Yb, sinv, rp, col);
    }
    float lg = S * smm[j] * 10.0f;
    logit[q] = lg;
    lmax = fmaxf(lmax, lg);
  }
  red[tid] = lmax; __syncthreads();
  for (int off = 128; off > 0; off >>= 1) {
    if (tid < off) red[tid] = fmaxf(red[tid], red[tid + off]);
    __syncthreads();
  }
  float M = red[0];
  __syncthreads();
  float ex[4];
  float lsum = 0.f;
#pragma unroll
  for (int q = 0; q < 4; ++q) { ex[q] = expf(logit[q] - M); lsum += ex[q]; }
  red[tid] = lsum; __syncthreads();
  for (int off = 128; off > 0; off >>= 1) {
    if (tid < off) red[tid] += red[tid + off];
    __syncthreads();
  }
  float inv = 1.0f / red[0];
  const int pos = ((i >> 5) + 1) * 34 + (i & 31) + 1;
  u16* dst = Apad + ((size_t)b * NPOS + pos) * 1024;
#pragma unroll
  for (int q = 0; q < 4; ++q) {
    int j = tid + (q << 8);
    dst[j] = f2bf(smm[j] * ex[q] * inv);
  }
}

// ---------------------------------------------------------------------------
// Paste MFMA: ypad[q,c] = sum_s sum_l Apad[q-ds, l] * x[l+ds, c]
// ---------------------------------------------------------------------------
__global__ __launch_bounds__(256) void paste_mfma(
    const u16* __restrict__ Apad, const u16* __restrict__ S3, u16* __restrict__ ypad) {
  const int b = blockIdx.z;
  const int m0 = blockIdx.x << 7;   // q tile (8)
  const int n0 = blockIdx.y << 7;   // c tile (2)
  const u16* Ab = Apad + (size_t)b * NPOS * 1024;
  __shared__ __align__(16) u16 As[128 * 64];
  __shared__ __align__(16) u16 Bs[128 * 64];
  const int tid = threadIdx.x;
  const int lane = tid & 63;
  const int wave = tid >> 6;
  const int wm = wave >> 1, wn = wave & 1;
  const int srow = lane >> 3;
  const int chunk = (lane & 7) ^ srow;
  const int cswz = chunk << 3;
  int pa[4], cb[4];
#pragma unroll
  for (int i = 0; i < 4; ++i) {
    pa[i] = posOf(m0 + wave * 32 + i * 8 + srow);
    cb[i] = b * 256 + n0 + wave * 32 + i * 8 + srow;
  }
  int aidx[4][2], bidx[4][2];
#pragma unroll
  for (int f = 0; f < 4; ++f)
#pragma unroll
    for (int ks = 0; ks < 2; ++ks) {
      int ra = wm * 64 + f * 16 + (lane & 15);
      int rb = wn * 64 + f * 16 + (lane & 15);
      int k16 = ks * 4 + (lane >> 4);
      aidx[f][ks] = ra * 64 + ((k16 ^ (ra & 7)) << 3);
      bidx[f][ks] = rb * 64 + ((k16 ^ (rb & 7)) << 3);
    }
  f32x4 acc[4][4] = {};
  for (int s = 0; s < 9; ++s) {
    const int dh = s / 3 - 1, dw = s % 3 - 1;
    const int dpos = dh * 34 + dw;
    const u16* Sd = S3 + (size_t)(dw + 1) * S3STRIDE;
    for (int l0 = 0; l0 < 1024; l0 += 64) {
      int rr = (l0 >> 5) + (chunk >> 2) + 1 + dh;
      int boff = rr * 32 + ((chunk & 3) << 3);
      __syncthreads();
#pragma unroll
      for (int i = 0; i < 4; ++i) {
        gload16(Ab + (size_t)(pa[i] - dpos) * 1024 + l0 + cswz, &As[(wave * 32 + i * 8) * 64]);
        gload16(Sd + (size_t)cb[i] * 1088 + boff, &Bs[(wave * 32 + i * 8) * 64]);
      }
      __syncthreads();
#pragma unroll
      for (int ks = 0; ks < 2; ++ks) {
        bf16x8 a[4], bb[4];
#pragma unroll
        for (int f = 0; f < 4; ++f) a[f] = *(const bf16x8*)(As + aidx[f][ks]);
#pragma unroll
        for (int f = 0; f < 4; ++f) bb[f] = *(const bf16x8*)(Bs + bidx[f][ks]);
#pragma unroll
        for (int mi = 0; mi < 4; ++mi)
#pragma unroll
          for (int ni = 0; ni < 4; ++ni)
            acc[mi][ni] = __builtin_amdgcn_mfma_f32_16x16x32_bf16(a[mi], bb[ni], acc[mi][ni], 0, 0, 0);
      }
    }
  }
  u16* yb = ypad + (size_t)b * NPOS * 256;
  const int r0 = (lane >> 4) << 2;
#pragma unroll
  for (int mi = 0; mi < 4; ++mi) {
    int qb = m0 + wm * 64 + mi * 16 + r0;
#pragma unroll
    for (int ni = 0; ni < 4; ++ni) {
      int c = n0 + wn * 64 + ni * 16 + (lane & 15);
#pragma unroll
      for (int r = 0; r < 4; ++r)
        yb[(size_t)posOf(qb + r) * 256 + c] = f2bf(acc[mi][ni][r]);
    }
  }
}

// ---------------------------------------------------------------------------
// ycat (= [ypad | xpad]) x wT GEMM body (taps S_FIRST..S_FIRST+S_COUNT-1)
// ---------------------------------------------------------------------------
template <int S_FIRST, int S_COUNT, int KW>
__device__ __forceinline__ void conv_body(
    const u16* __restrict__ ypad_b, const u16* __restrict__ xpad_b,
    const u16* __restrict__ wT, float* __restrict__ dst_b, int m0, int n0) {
  __shared__ __align__(16) u16 As[128 * 64];
  __shared__ __align__(16) u16 Bs[128 * 64];
  const int tid = threadIdx.x;
  const int lane = tid & 63;
  const int wave = tid >> 6;
  const int wm = wave >> 1, wn = wave & 1;
  const int srow = lane >> 3;
  const int cswz = ((lane & 7) ^ srow) << 3;
  int pa[4], co[4];
#pragma unroll
  for (int i = 0; i < 4; ++i) {
    pa[i] = posOf(m0 + wave * 32 + i * 8 + srow);
    co[i] = n0 + wave * 32 + i * 8 + srow;
  }
  int aidx[4][2], bidx[4][2];
#pragma unroll
  for (int f = 0; f < 4; ++f)
#pragma unroll
    for (int ks = 0; ks < 2; ++ks) {
      int ra = wm * 64 + f * 16 + (lane & 15);
      int rb = wn * 64 + f * 16 + (lane & 15);
      int k16 = ks * 4 + (lane >> 4);
      aidx[f][ks] = ra * 64 + ((k16 ^ (ra & 7)) << 3);
      bidx[f][ks] = rb * 64 + ((k16 ^ (rb & 7)) << 3);
    }
  f32x4 acc[4][4] = {};
  for (int sr = 0; sr < S_COUNT; ++sr) {
    const int s = S_FIRST + sr;
    const int dpos = (s / 3 - 1) * 34 + (s % 3 - 1);
    for (int c0 = 0; c0 < 512; c0 += 64) {
      const u16* base = (c0 < 256) ? ypad_b : xpad_b;
      const int coff = c0 & 255;
      __syncthreads();
#pragma unroll
      for (int i = 0; i < 4; ++i) {
        gload16(base + (size_t)(pa[i] + dpos) * 256 + coff + cswz, &As[(wave * 32 + i * 8) * 64]);
        gload16(wT + (size_t)co[i] * KW + sr * 512 + c0 + cswz, &Bs[(wave * 32 + i * 8) * 64]);
      }
      __syncthreads();
#pragma unroll
      for (int ks = 0; ks < 2; ++ks) {
        bf16x8 a[4], bb[4];
#pragma unroll
        for (int f = 0; f < 4; ++f) a[f] = *(const bf16x8*)(As + aidx[f][ks]);
#pragma unroll
        for (int f = 0; f < 4; ++f) bb[f] = *(const bf16x8*)(Bs + bidx[f][ks]);
#pragma unroll
        for (int mi = 0; mi < 4; ++mi)
#pragma unroll
          for (int ni = 0; ni < 4; ++ni)
            acc[mi][ni] = __builtin_amdgcn_mfma_f32_16x16x32_bf16(a[mi], bb[ni], acc[mi][ni], 0, 0, 0);
      }
    }
  }
  const int r0 = (lane >> 4) << 2;
#pragma unroll
  for (int mi = 0; mi < 4; ++mi) {
    int qb = m0 + wm * 64 + mi * 16 + r0;
#pragma unroll
    for (int ni = 0; ni < 4; ++ni) {
      int cc = n0 + wn * 64 + ni * 16 + (lane & 15);
#pragma unroll
      for (int r = 0; r < 4; ++r)
        dst_b[(size_t)(qb + r) * 256 + cc] = acc[mi][ni][r];
    }
  }
}

__global__ __launch_bounds__(256) void conv_big(
    const u16* __restrict__ ypad, const u16* __restrict__ xpad,
    const u16* __restrict__ w0T, const u16* __restrict__ w2T,
    float* __restrict__ c0buf, float* __restrict__ c2buf) {
  int z = blockIdx.z;
  int b = z >> 1, sel = z & 1;
  conv_body<0, 9, 4608>(ypad + (size_t)b * NPOS * 256, xpad + (size_t)b * NPOS * 256,
                        sel ? w2T : w0T,
                        (sel ? c2buf : c0buf) + (size_t)b * 1024 * 256,
                        blockIdx.x << 7, blockIdx.y << 7);
}

__global__ __launch_bounds__(256) void conv_g1(
    const u16* __restrict__ ypad, const u16* __restrict__ xpad,
    const u16* __restrict__ w1T, float* __restrict__ c1buf) {
  int b = blockIdx.z;
  conv_body<4, 1, 512>(ypad + (size_t)b * NPOS * 256, xpad + (size_t)b * NPOS * 256,
                       w1T, c1buf + (size_t)b * 1024 * 256,
                       blockIdx.x << 7, blockIdx.y << 7);
}

// out = 0.5*(sig(c1+b1)+sig(c2+b2))*(c0+b0)
__global__ __launch_bounds__(256) void gate_out(
    const float* __restrict__ c0buf, const float* __restrict__ c1buf,
    const float* __restrict__ c2buf, const float* __restrict__ b0,
    const float* __restrict__ b1, const float* __restrict__ b2,
    float* __restrict__ out) {
  size_t i4 = ((size_t)blockIdx.x * 256 + threadIdx.x) * 4;
  int co = (int)(i4 & 255);
  float4 v0 = *(const float4*)(c0buf + i4);
  float4 v1 = *(const float4*)(c1buf + i4);
  float4 v2 = *(const float4*)(c2buf + i4);
  float4 q0 = *(const float4*)(b0 + co);
  float4 q1 = *(const float4*)(b1 + co);
  float4 q2 = *(const float4*)(b2 + co);
  float4 o;
  const float* pv0 = (const float*)&v0; const float* pv1 = (const float*)&v1;
  const float* pv2 = (const float*)&v2; const float* pq0 = (const float*)&q0;
  const float* pq1 = (const float*)&q1; const float* pq2 = (const float*)&q2;
  float* po = (float*)&o;
#pragma unroll
  for (int j = 0; j < 4; ++j) {
    float g1 = 1.f / (1.f + expf(-(pv1[j] + pq1[j])));
    float g2 = 1.f / (1.f + expf(-(pv2[j] + pq2[j])));
    po[j] = 0.5f * (g1 + g2) * (pv0[j] + pq0[j]);
  }
  *(float4*)(out + i4) = o;
}

// ---------------------------------------------------------------------------

extern "C" void kernel_launch(void* const* d_in, const int* in_sizes, int n_in,
                              void* d_out, int out_size, void* d_ws, size_t ws_size,
                              hipStream_t stream) {
  const float* x = (const float*)d_in[0];
  const float* mask = (const float*)d_in[1];
  const float* conv_w = (const float*)d_in[2];
  const float* conv_b = (const float*)d_in[3];
  const float* conv1_w = (const float*)d_in[4];
  const float* conv1_b = (const float*)d_in[5];
  const float* conv2_w = (const float*)d_in[6];
  const float* conv2_b = (const float*)d_in[7];
  float* out = (float*)d_out;
  char* wsb = (char*)d_ws;

  // workspace layout (bytes)
  float* c0buf = (float*)(wsb + 0);               //  8 MB (aliases G)
  float* c1buf = (float*)(wsb + 8388608);         //  8 MB (aliases G)
  float* c2buf = (float*)(wsb + 16777216);        //  8 MB
  u16* G      = (u16*)(wsb + 0);                  // 16 MB bf16 scores (dead after fuse)
  u16* Apad   = (u16*)(wsb + 25165824);           // 18.94 MB
  u16* xpad   = (u16*)(wsb + 44105728);           //  4.73 MB
  u16* S3     = (u16*)(wsb + 48840704);           // 13.37 MB (3 shifted copies)
  u16* ypad   = (u16*)(wsb + 62210048);           //  4.73 MB
  u16* w0T    = (u16*)(wsb + 66945024);           //  2.36 MB
  u16* w2T    = (u16*)(wsb + 69304320);           //  2.36 MB
  u16* w1T    = (u16*)(wsb + 71663616);           //  0.26 MB
  float* invn = (float*)(wsb + 71925760);
  float* mmb  = (float*)(wsb + 71958528);

  // zero padded buffers (Apad, xpad, S3, ypad are contiguous)
  hipMemsetAsync(wsb + 25165824, 0, 41779200, stream);

  cast_x<<<256, 256, 0, stream>>>(x, xpad, S3);
  wtrans<<<144, 256, 0, stream>>>(conv_w, w0T, 4608);
  wtrans<<<144, 256, 0, stream>>>(conv2_w, w2T, 4608);
  wtrans<<<16, 256, 0, stream>>>(conv1_w, w1T, 512);

  gram_mfma<<<dim3(8, 8, 8), 256, 0, stream>>>(xpad, G);
  norm_mm<<<32, 256, 0, stream>>>(G, mask, invn, mmb, out + 2097152);
  fuse_softmax<<<8192, 256, 0, stream>>>(G, invn, mmb, Apad);
  paste_mfma<<<dim3(8, 2, 8), 256, 0, stream>>>(Apad, S3, ypad);
  conv_g1<<<dim3(8, 2, 8), 256, 0, stream>>>(ypad, xpad, w1T, c1buf);
  conv_big<<<dim3(8, 2, 16), 256, 0, stream>>>(ypad, xpad, w0T, w2T, c0buf, c2buf);
  gate_out<<<2048, 256, 0, stream>>>(c0buf, c1buf, c2buf, conv_b, conv1_b, conv2_b, out);
}

// Round 4
// 404.398 us; speedup vs baseline: 4.7176x; 1.0942x over previous
//
#include <hip/hip_runtime.h>
#include <math.h>

typedef unsigned short u16;
typedef __bf16 bf16x8 __attribute__((ext_vector_type(8)));
typedef float f32x4 __attribute__((ext_vector_type(4)));

#define NPOS 1156  // 34*34 padded positions

__device__ __forceinline__ u16 f2bf(float f) {
  unsigned int u = __builtin_bit_cast(unsigned int, f);
  return (u16)((u + 0x7FFFu + ((u >> 16) & 1u)) >> 16);
}
__device__ __forceinline__ float bf2f(u16 v) {
  unsigned int u = ((unsigned int)v) << 16;
  return __builtin_bit_cast(float, u);
}
__device__ __forceinline__ void gload16(const void* g, void* l) {
  __builtin_amdgcn_global_load_lds(
      (const __attribute__((address_space(1))) void*)g,
      (__attribute__((address_space(3))) void*)l, 16, 0, 0);
}
__device__ __forceinline__ int posOf(int p) {  // interior padded position
  return ((p >> 5) + 1) * 34 + (p & 31) + 1;
}

// ---------------------------------------------------------------------------
// cast x -> xpad [b][34][34][256] bf16 (zero border via memset) and
// xT [b][256][1024] bf16 (channel-major, for paste B-operand)
// ---------------------------------------------------------------------------
__global__ __launch_bounds__(256) void cast_x(
    const float* __restrict__ x, u16* __restrict__ xpad, u16* __restrict__ xT) {
  int blk = blockIdx.x;  // b*32 + h
  int b = blk >> 5, h = blk & 31;
  __shared__ u16 T[256][33];
  const float* xrow = x + ((size_t)b * 1024 + h * 32) * 256;
  int tid = threadIdx.x;
  for (int idx = tid; idx < 8192; idx += 256) {
    int w = idx >> 8, c = idx & 255;
    u16 v = f2bf(xrow[(size_t)w * 256 + c]);
    T[c][w] = v;
    xpad[((size_t)b * NPOS + (h + 1) * 34 + (w + 1)) * 256 + c] = v;
  }
  __syncthreads();
  int c = tid;
  unsigned int* dp = (unsigned int*)(xT + ((size_t)(b * 256 + c)) * 1024 + h * 32);
  const unsigned int* sp = (const unsigned int*)&T[c][0];
#pragma unroll
  for (int u = 0; u < 16; ++u) dp[u] = sp[u];
}

// weight transpose: src f32 [K][256] -> dst bf16 [256][K]
__global__ __launch_bounds__(256) void wtrans(
    const float* __restrict__ src, u16* __restrict__ dst, int K) {
  int k0 = blockIdx.x * 32;
  __shared__ u16 T[256][34];
  int tid = threadIdx.x;
  for (int idx = tid; idx < 8192; idx += 256) {
    int kr = idx >> 8, c = idx & 255;
    T[c][kr] = f2bf(src[(size_t)(k0 + kr) * 256 + c]);
  }
  __syncthreads();
  int c = tid;
  unsigned int* dp = (unsigned int*)(dst + (size_t)c * K + k0);
  const unsigned int* sp = (const unsigned int*)&T[c][0];
#pragma unroll
  for (int u = 0; u < 16; ++u) dp[u] = sp[u];
}

// ---------------------------------------------------------------------------
// Gbase[b,p,l] = sum_c x[p,c]*x[l,c]  (interior only), K=256 -> f32
// 128x128 tile, 4 waves (64x64 each)
// ---------------------------------------------------------------------------
__global__ __launch_bounds__(256) void gram_base(
    const u16* __restrict__ xpad, float* __restrict__ G) {
  const int b = blockIdx.z;
  const int m0 = blockIdx.x << 7;
  const int n0 = blockIdx.y << 7;
  const u16* xb = xpad + (size_t)b * NPOS * 256;
  __shared__ __align__(16) u16 As[128 * 64];
  __shared__ __align__(16) u16 Bs[128 * 64];
  const int tid = threadIdx.x;
  const int lane = tid & 63;
  const int wave = tid >> 6;
  const int wm = wave >> 1, wn = wave & 1;
  const int srow = lane >> 3;
  const int cswz = ((lane & 7) ^ srow) << 3;
  int pa[4], pb[4];
#pragma unroll
  for (int i = 0; i < 4; ++i) {
    pa[i] = posOf(m0 + wave * 32 + i * 8 + srow);
    pb[i] = posOf(n0 + wave * 32 + i * 8 + srow);
  }
  int aidx[4][2], bidx[4][2];
#pragma unroll
  for (int f = 0; f < 4; ++f)
#pragma unroll
    for (int ks = 0; ks < 2; ++ks) {
      int ra = wm * 64 + f * 16 + (lane & 15);
      int rb = wn * 64 + f * 16 + (lane & 15);
      int k16 = ks * 4 + (lane >> 4);
      aidx[f][ks] = ra * 64 + ((k16 ^ (ra & 7)) << 3);
      bidx[f][ks] = rb * 64 + ((k16 ^ (rb & 7)) << 3);
    }
  f32x4 acc[4][4] = {};
  for (int c0 = 0; c0 < 256; c0 += 64) {
    __syncthreads();
#pragma unroll
    for (int i = 0; i < 4; ++i) {
      gload16(xb + (size_t)pa[i] * 256 + c0 + cswz, &As[(wave * 32 + i * 8) * 64]);
      gload16(xb + (size_t)pb[i] * 256 + c0 + cswz, &Bs[(wave * 32 + i * 8) * 64]);
    }
    __syncthreads();
#pragma unroll
    for (int ks = 0; ks < 2; ++ks) {
      bf16x8 a[4], bb[4];
#pragma unroll
      for (int f = 0; f < 4; ++f) a[f] = *(const bf16x8*)(As + aidx[f][ks]);
#pragma unroll
      for (int f = 0; f < 4; ++f) bb[f] = *(const bf16x8*)(Bs + bidx[f][ks]);
#pragma unroll
      for (int mi = 0; mi < 4; ++mi)
#pragma unroll
        for (int ni = 0; ni < 4; ++ni)
          acc[mi][ni] = __builtin_amdgcn_mfma_f32_16x16x32_bf16(a[mi], bb[ni], acc[mi][ni], 0, 0, 0);
    }
  }
  float* Gb = G + ((size_t)b << 20);
  const int r0 = (lane >> 4) << 2;
  const int cb0 = n0 + wn * 64 + (lane & 15);
#pragma unroll
  for (int mi = 0; mi < 4; ++mi) {
    int row = m0 + wm * 64 + mi * 16 + r0;
#pragma unroll
    for (int ni = 0; ni < 4; ++ni) {
      int col = cb0 + ni * 16;
#pragma unroll
      for (int r = 0; r < 4; ++r)
        Gb[(size_t)(row + r) * 1024 + col] = acc[mi][ni][r];
    }
  }
}

// ---------------------------------------------------------------------------
// invn from 9-tap diagonal of Gbase (f32); mm; ones tail
// ---------------------------------------------------------------------------
__global__ __launch_bounds__(256) void norm_mm(
    const float* __restrict__ G, const float* __restrict__ mask,
    float* __restrict__ invn, float* __restrict__ mm, float* __restrict__ ones_out) {
  int idx = blockIdx.x * 256 + threadIdx.x;
  int b = idx >> 10, l = idx & 1023;
  const float* Gb = G + ((size_t)b << 20);
  int lh = l >> 5, lw = l & 31;
  float d = 0.f;
#pragma unroll
  for (int dh = -1; dh <= 1; ++dh)
#pragma unroll
    for (int dw = -1; dw <= 1; ++dw) {
      if ((unsigned)(lh + dh) < 32u && (unsigned)(lw + dw) < 32u) {
        int dl = dh * 32 + dw;
        d += Gb[(size_t)(l + dl) * 1025];
      }
    }
  invn[idx] = 1.0f / fmaxf(sqrtf(d), 1e-4f);
  float s = 0.f;
  for (int dh = -1; dh <= 1; ++dh)
    for (int dw = -1; dw <= 1; ++dw) {
      int hh = lh + dh, wv = lw + dw;
      if (hh >= 0 && hh < 32 && wv >= 0 && wv < 32) s += mask[b * 1024 + hh * 32 + wv];
    }
  mm[idx] = ((s / 9.0f) == 1.0f) ? 1.0f : 0.0f;
  ones_out[idx] = 1.0f;
}

// ---------------------------------------------------------------------------
// Ytilde[p,l] = invn[l] * sum_s Gbase[p+ds, l+ds]   (9-tap diag stencil) f32
// ---------------------------------------------------------------------------
__global__ __launch_bounds__(256) void patch_norm(
    const float* __restrict__ Gbase, const float* __restrict__ invn,
    float* __restrict__ Yt) {
  const int b = blockIdx.y;
  const int p0 = blockIdx.x << 3;
  const float* Gb = Gbase + ((size_t)b << 20);
  float* Yb = Yt + ((size_t)b << 20);
  const float* inb = invn + (b << 10);
  const int tid = threadIdx.x;
  for (int r = 0; r < 8; ++r) {
    int p = p0 + r;
    int ph = p >> 5, pw = p & 31;
    for (int l = tid; l < 1024; l += 256) {
      int lh = l >> 5, lw = l & 31;
      float s = 0.f;
#pragma unroll
      for (int dh = -1; dh <= 1; ++dh)
#pragma unroll
        for (int dw = -1; dw <= 1; ++dw) {
          if ((unsigned)(ph + dh) < 32u && (unsigned)(pw + dw) < 32u &&
              (unsigned)(lh + dh) < 32u && (unsigned)(lw + dw) < 32u) {
            int dl = dh * 32 + dw;
            s += Gb[(size_t)(p + dl) * 1024 + (l + dl)];
          }
        }
      Yb[(size_t)p * 1024 + l] = s * inb[l];
    }
  }
}

// ---------------------------------------------------------------------------
// Fused diag-fuse + mask + softmax -> A [b][1024][1024] bf16 (unpadded)
// ---------------------------------------------------------------------------
__device__ __forceinline__ float z1f(const float* __restrict__ Yb, int r, int s2) {
  float v = Yb[(size_t)r * 1024 + s2];
  if (r >= 1 && s2 >= 1) v += Yb[(size_t)(r - 1) * 1024 + (s2 - 1)];
  if (r <= 1022 && s2 <= 1022) v += Yb[(size_t)(r + 1) * 1024 + (s2 + 1)];
  return v;
}

__global__ __launch_bounds__(256) void fuse_softmax(
    const float* __restrict__ Yt, const float* __restrict__ mm, u16* __restrict__ A) {
  const int bi = blockIdx.x;
  const int b = bi >> 10, i = bi & 1023;
  const float* Yb = Yt + ((size_t)b << 20);
  __shared__ float smm[1024];
  __shared__ float red[256];
  const int tid = threadIdx.x;
  for (int t = tid; t < 1024; t += 256) smm[t] = mm[(b << 10) + t];
  __syncthreads();
  const int si = ((i & 31) << 5) | (i >> 5);
  const int rm = (si >= 1) ? ((((si - 1) & 31) << 5) | ((si - 1) >> 5)) : -1;
  const int rp = (si <= 1022) ? ((((si + 1) & 31) << 5) | ((si + 1) >> 5)) : -1;
  float logit[4];
  float lmax = -3.0e38f;
#pragma unroll
  for (int q = 0; q < 4; ++q) {
    int j = tid + (q << 8);
    int sj = ((j & 31) << 5) | (j >> 5);
    float S = z1f(Yb, i, j);
    if (rm >= 0 && sj >= 1) {
      int col = (((sj - 1) & 31) << 5) | ((sj - 1) >> 5);
      S += z1f(Yb, rm, col);
    }
    if (rp >= 0 && sj <= 1022) {
      int col = (((sj + 1) & 31) << 5) | ((sj + 1) >> 5);
      S += z1f(Yb, rp, col);
    }
    float lg = S * smm[j] * 10.0f;
    logit[q] = lg;
    lmax = fmaxf(lmax, lg);
  }
  red[tid] = lmax; __syncthreads();
  for (int off = 128; off > 0; off >>= 1) {
    if (tid < off) red[tid] = fmaxf(red[tid], red[tid + off]);
    __syncthreads();
  }
  float M = red[0];
  __syncthreads();
  float ex[4];
  float lsum = 0.f;
#pragma unroll
  for (int q = 0; q < 4; ++q) { ex[q] = expf(logit[q] - M); lsum += ex[q]; }
  red[tid] = lsum; __syncthreads();
  for (int off = 128; off > 0; off >>= 1) {
    if (tid < off) red[tid] += red[tid + off];
    __syncthreads();
  }
  float inv = 1.0f / red[0];
  u16* dst = A + ((size_t)b << 20) + (size_t)i * 1024;
#pragma unroll
  for (int q = 0; q < 4; ++q) {
    int j = tid + (q << 8);
    dst[j] = f2bf(smm[j] * ex[q] * inv);
  }
}

// ---------------------------------------------------------------------------
// Afuse[q,l] = sum_s A[q-ds, l-ds]   (9-tap diag stencil, negative shifts)
// ---------------------------------------------------------------------------
__global__ __launch_bounds__(256) void afuse_stencil(
    const u16* __restrict__ A, u16* __restrict__ Afuse) {
  const int b = blockIdx.y;
  const int q0 = blockIdx.x << 3;
  const u16* Ab = A + ((size_t)b << 20);
  u16* Fb = Afuse + ((size_t)b << 20);
  const int tid = threadIdx.x;
  for (int r = 0; r < 8; ++r) {
    int q = q0 + r;
    int qh = q >> 5, qw = q & 31;
    for (int l = tid; l < 1024; l += 256) {
      int lh = l >> 5, lw = l & 31;
      float s = 0.f;
#pragma unroll
      for (int dh = -1; dh <= 1; ++dh)
#pragma unroll
        for (int dw = -1; dw <= 1; ++dw) {
          if ((unsigned)(qh - dh) < 32u && (unsigned)(qw - dw) < 32u &&
              (unsigned)(lh - dh) < 32u && (unsigned)(lw - dw) < 32u) {
            int dl = dh * 32 + dw;
            s += bf2f(Ab[(size_t)(q - dl) * 1024 + (l - dl)]);
          }
        }
      Fb[(size_t)q * 1024 + l] = f2bf(s);
    }
  }
}

// ---------------------------------------------------------------------------
// paste GEMM: ypad[q,c] = sum_l Afuse[q,l] * x[l,c]; M-tile 64, N-tile 128, K=1024
// ---------------------------------------------------------------------------
__global__ __launch_bounds__(256) void paste_gemm(
    const u16* __restrict__ Afuse, const u16* __restrict__ xT, u16* __restrict__ ypad) {
  const int bm0 = blockIdx.x << 6;  // global row 0..8191
  const int b = bm0 >> 10;
  const int q0 = bm0 & 1023;
  const int n0 = blockIdx.y << 7;
  const u16* Ab = Afuse + ((size_t)b << 20);
  const u16* xTb = xT + ((size_t)b << 18);
  __shared__ __align__(16) u16 As[64 * 64];
  __shared__ __align__(16) u16 Bs[128 * 64];
  const int tid = threadIdx.x;
  const int lane = tid & 63;
  const int wave = tid >> 6;
  const int wm = wave >> 1, wn = wave & 1;
  const int srow = lane >> 3;
  const int cswz = ((lane & 7) ^ srow) << 3;
  int aidx[2][2], bidx[4][2];
#pragma unroll
  for (int ks = 0; ks < 2; ++ks) {
    int k16 = ks * 4 + (lane >> 4);
#pragma unroll
    for (int f = 0; f < 2; ++f) {
      int ra = wm * 32 + f * 16 + (lane & 15);
      aidx[f][ks] = ra * 64 + ((k16 ^ (ra & 7)) << 3);
    }
#pragma unroll
    for (int f = 0; f < 4; ++f) {
      int rb = wn * 64 + f * 16 + (lane & 15);
      bidx[f][ks] = rb * 64 + ((k16 ^ (rb & 7)) << 3);
    }
  }
  f32x4 acc[2][4] = {};
  for (int l0 = 0; l0 < 1024; l0 += 64) {
    __syncthreads();
#pragma unroll
    for (int i = 0; i < 2; ++i) {
      int ar = wave * 16 + i * 8 + srow;
      gload16(Ab + (size_t)(q0 + ar) * 1024 + l0 + cswz, &As[ar * 64]);
    }
#pragma unroll
    for (int i = 0; i < 4; ++i) {
      int br = wave * 32 + i * 8 + srow;
      gload16(xTb + (size_t)(n0 + br) * 1024 + l0 + cswz, &Bs[br * 64]);
    }
    __syncthreads();
#pragma unroll
    for (int ks = 0; ks < 2; ++ks) {
      bf16x8 a[2], bb[4];
#pragma unroll
      for (int f = 0; f < 2; ++f) a[f] = *(const bf16x8*)(As + aidx[f][ks]);
#pragma unroll
      for (int f = 0; f < 4; ++f) bb[f] = *(const bf16x8*)(Bs + bidx[f][ks]);
#pragma unroll
      for (int mi = 0; mi < 2; ++mi)
#pragma unroll
        for (int ni = 0; ni < 4; ++ni)
          acc[mi][ni] = __builtin_amdgcn_mfma_f32_16x16x32_bf16(a[mi], bb[ni], acc[mi][ni], 0, 0, 0);
    }
  }
  u16* yb = ypad + (size_t)b * NPOS * 256;
  const int r0 = (lane >> 4) << 2;
#pragma unroll
  for (int mi = 0; mi < 2; ++mi) {
    int qb = q0 + wm * 32 + mi * 16 + r0;
#pragma unroll
    for (int ni = 0; ni < 4; ++ni) {
      int c = n0 + wn * 64 + ni * 16 + (lane & 15);
#pragma unroll
      for (int r = 0; r < 4; ++r)
        yb[(size_t)posOf(qb + r) * 256 + c] = f2bf(acc[mi][ni][r]);
    }
  }
}

// ---------------------------------------------------------------------------
// final fused: acc0 = conv_w (9 taps), acc1 = conv1_w (center), acc2 = conv2_w
// out = 0.5*(sig(acc1+b1)+sig(acc2+b2)) * (acc0+b0)
// tile M128 x N64, K = 9*512 (+512 center for acc1)
// ---------------------------------------------------------------------------
__global__ __launch_bounds__(256) void final_fused(
    const u16* __restrict__ ypad, const u16* __restrict__ xpad,
    const u16* __restrict__ w0T, const u16* __restrict__ w1T,
    const u16* __restrict__ w2T,
    const float* __restrict__ b0, const float* __restrict__ b1,
    const float* __restrict__ b2, float* __restrict__ out) {
  const int m0 = blockIdx.x << 7;
  const int b = m0 >> 10;
  const int q0 = m0 & 1023;
  const int n0 = blockIdx.y << 6;
  const u16* yb = ypad + (size_t)b * NPOS * 256;
  const u16* xb = xpad + (size_t)b * NPOS * 256;
  __shared__ __align__(16) u16 As[128 * 64];
  __shared__ __align__(16) u16 B0s[64 * 64];
  __shared__ __align__(16) u16 B1s[64 * 64];
  __shared__ __align__(16) u16 B2s[64 * 64];
  const int tid = threadIdx.x;
  const int lane = tid & 63;
  const int wave = tid >> 6;
  const int wm = wave >> 1, wn = wave & 1;
  const int srow = lane >> 3;
  const int cswz = ((lane & 7) ^ srow) << 3;
  int posA[4];
#pragma unroll
  for (int i = 0; i < 4; ++i) posA[i] = posOf(q0 + wave * 32 + i * 8 + srow);
  int aidx[4][2], bidx[2][2];
#pragma unroll
  for (int ks = 0; ks < 2; ++ks) {
    int k16 = ks * 4 + (lane >> 4);
#pragma unroll
    for (int f = 0; f < 4; ++f) {
      int ra = wm * 64 + f * 16 + (lane & 15);
      aidx[f][ks] = ra * 64 + ((k16 ^ (ra & 7)) << 3);
    }
#pragma unroll
    for (int f = 0; f < 2; ++f) {
      int rb = wn * 32 + f * 16 + (lane & 15);
      bidx[f][ks] = rb * 64 + ((k16 ^ (rb & 7)) << 3);
    }
  }
  f32x4 acc0[4][2] = {}, acc1[4][2] = {}, acc2[4][2] = {};
  for (int s = 0; s < 9; ++s) {
    const int dpos = (s / 3 - 1) * 34 + (s % 3 - 1);
    for (int c0 = 0; c0 < 512; c0 += 64) {
      const u16* base = (c0 < 256) ? yb : xb;
      const int coff = c0 & 255;
      __syncthreads();
#pragma unroll
      for (int i = 0; i < 4; ++i) {
        int ar = wave * 32 + i * 8 + srow;
        gload16(base + (size_t)(posA[i] + dpos) * 256 + coff + cswz, &As[ar * 64]);
      }
#pragma unroll
      for (int i = 0; i < 2; ++i) {
        int br = wave * 16 + i * 8 + srow;
        size_t krow = (size_t)(n0 + br) * 4608 + s * 512 + c0 + cswz;
        gload16(w0T + krow, &B0s[br * 64]);
        gload16(w2T + krow, &B2s[br * 64]);
      }
      if (s == 4) {
#pragma unroll
        for (int i = 0; i < 2; ++i) {
          int br = wave * 16 + i * 8 + srow;
          gload16(w1T + (size_t)(n0 + br) * 512 + c0 + cswz, &B1s[br * 64]);
        }
      }
      __syncthreads();
#pragma unroll
      for (int ks = 0; ks < 2; ++ks) {
        bf16x8 a[4], v0[2], v2[2];
#pragma unroll
        for (int f = 0; f < 4; ++f) a[f] = *(const bf16x8*)(As + aidx[f][ks]);
#pragma unroll
        for (int f = 0; f < 2; ++f) v0[f] = *(const bf16x8*)(B0s + bidx[f][ks]);
#pragma unroll
        for (int f = 0; f < 2; ++f) v2[f] = *(const bf16x8*)(B2s + bidx[f][ks]);
#pragma unroll
        for (int mi = 0; mi < 4; ++mi)
#pragma unroll
          for (int ni = 0; ni < 2; ++ni) {
            acc0[mi][ni] = __builtin_amdgcn_mfma_f32_16x16x32_bf16(a[mi], v0[ni], acc0[mi][ni], 0, 0, 0);
            acc2[mi][ni] = __builtin_amdgcn_mfma_f32_16x16x32_bf16(a[mi], v2[ni], acc2[mi][ni], 0, 0, 0);
          }
        if (s == 4) {
          bf16x8 v1[2];
#pragma unroll
          for (int f = 0; f < 2; ++f) v1[f] = *(const bf16x8*)(B1s + bidx[f][ks]);
#pragma unroll
          for (int mi = 0; mi < 4; ++mi)
#pragma unroll
            for (int ni = 0; ni < 2; ++ni)
              acc1[mi][ni] = __builtin_amdgcn_mfma_f32_16x16x32_bf16(a[mi], v1[ni], acc1[mi][ni], 0, 0, 0);
        }
      }
    }
  }
  const int r0 = (lane >> 4) << 2;
#pragma unroll
  for (int ni = 0; ni < 2; ++ni) {
    int co = n0 + wn * 32 + ni * 16 + (lane & 15);
    float q0b = b0[co], q1b = b1[co], q2b = b2[co];
#pragma unroll
    for (int mi = 0; mi < 4; ++mi) {
      int m = m0 + wm * 64 + mi * 16 + r0;
#pragma unroll
      for (int r = 0; r < 4; ++r) {
        float g1 = 1.f / (1.f + expf(-(acc1[mi][ni][r] + q1b)));
        float g2 = 1.f / (1.f + expf(-(acc2[mi][ni][r] + q2b)));
        out[(size_t)(m + r) * 256 + co] = 0.5f * (g1 + g2) * (acc0[mi][ni][r] + q0b);
      }
    }
  }
}

// ---------------------------------------------------------------------------

extern "C" void kernel_launch(void* const* d_in, const int* in_sizes, int n_in,
                              void* d_out, int out_size, void* d_ws, size_t ws_size,
                              hipStream_t stream) {
  const float* x = (const float*)d_in[0];
  const float* mask = (const float*)d_in[1];
  const float* conv_w = (const float*)d_in[2];
  const float* conv_b = (const float*)d_in[3];
  const float* conv1_w = (const float*)d_in[4];
  const float* conv1_b = (const float*)d_in[5];
  const float* conv2_w = (const float*)d_in[6];
  const float* conv2_b = (const float*)d_in[7];
  float* out = (float*)d_out;
  char* wsb = (char*)d_ws;

  // workspace layout (bytes). Gbase (f32, 33.55 MB) is dead after patch_norm
  // + norm_mm; A and Afuse (16.78 MB each) alias its region.
  float* Gbase = (float*)(wsb + 0);        // [0, 33554432)
  u16* A       = (u16*)(wsb + 0);          // [0, 16777216)      aliases Gbase
  u16* Afuse   = (u16*)(wsb + 16777216);   // [16777216, 33554432) aliases Gbase
  float* Yt    = (float*)(wsb + 33554432); // [33554432, 67108864) f32
  u16* xpad    = (u16*)(wsb + 67108864);   //  4.73 MB
  u16* ypad    = (u16*)(wsb + 71843840);   //  4.73 MB
  u16* xT      = (u16*)(wsb + 76578816);   //  4.19 MB
  u16* w0T     = (u16*)(wsb + 80773120);   //  2.36 MB
  u16* w2T     = (u16*)(wsb + 83132416);   //  2.36 MB
  u16* w1T     = (u16*)(wsb + 85491712);   //  0.26 MB
  float* invn  = (float*)(wsb + 85753856);
  float* mmb   = (float*)(wsb + 85786624);

  hipMemsetAsync(wsb + 67108864, 0, 9469952, stream);  // xpad + ypad borders

  cast_x<<<256, 256, 0, stream>>>(x, xpad, xT);
  wtrans<<<144, 256, 0, stream>>>(conv_w, w0T, 4608);
  wtrans<<<144, 256, 0, stream>>>(conv2_w, w2T, 4608);
  wtrans<<<16, 256, 0, stream>>>(conv1_w, w1T, 512);

  gram_base<<<dim3(8, 8, 8), 256, 0, stream>>>(xpad, Gbase);
  norm_mm<<<32, 256, 0, stream>>>(Gbase, mask, invn, mmb, out + 2097152);
  patch_norm<<<dim3(128, 8), 256, 0, stream>>>(Gbase, invn, Yt);
  fuse_softmax<<<8192, 256, 0, stream>>>(Yt, mmb, A);
  afuse_stencil<<<dim3(128, 8), 256, 0, stream>>>(A, Afuse);
  paste_gemm<<<dim3(128, 2), 256, 0, stream>>>(Afuse, xT, ypad);
  final_fused<<<dim3(64, 4), 256, 0, stream>>>(ypad, xpad, w0T, w1T, w2T,
                                               conv_b, conv1_b, conv2_b, out);
}

// Round 5
// 299.971 us; speedup vs baseline: 6.3599x; 1.3481x over previous
//
#include <hip/hip_runtime.h>
#include <math.h>

typedef unsigned short u16;
typedef __bf16 bf16x8 __attribute__((ext_vector_type(8)));
typedef float f32x4 __attribute__((ext_vector_type(4)));

#define NPOS 1156           // 34*34 padded positions
#define GSTR 1160           // Gpad/Apad2 row stride (f32 elems)
#define GOFF (GSTR * 1156)  // per-batch Gpad elems = 1340960
#define YSTR 1032           // Ylin row stride
#define YOFF (YSTR * 1026)  // per-batch Ylin elems = 1058832
#define POS34(p) ((((p) >> 5) + 1) * 34 + ((p) & 31) + 1)

__device__ __constant__ const int kDiagOff[9] = {
    -35 * (GSTR + 1), -34 * (GSTR + 1), -33 * (GSTR + 1),
    -1 * (GSTR + 1),  0,                1 * (GSTR + 1),
    33 * (GSTR + 1),  34 * (GSTR + 1),  35 * (GSTR + 1)};

__device__ __forceinline__ u16 f2bf(float f) {
  unsigned int u = __builtin_bit_cast(unsigned int, f);
  return (u16)((u + 0x7FFFu + ((u >> 16) & 1u)) >> 16);
}
__device__ __forceinline__ float bf2f(u16 v) {
  unsigned int u = ((unsigned int)v) << 16;
  return __builtin_bit_cast(float, u);
}
__device__ __forceinline__ void gload16(const void* g, void* l) {
  __builtin_amdgcn_global_load_lds(
      (const __attribute__((address_space(1))) void*)g,
      (__attribute__((address_space(3))) void*)l, 16, 0, 0);
}
__device__ __forceinline__ int posOf(int p) { return POS34(p); }

// ---------------------------------------------------------------------------
// cast x -> xpad [b][34][34][256] bf16 and xT [b][256][1024] bf16
// ---------------------------------------------------------------------------
__global__ __launch_bounds__(256) void cast_x(
    const float* __restrict__ x, u16* __restrict__ xpad, u16* __restrict__ xT) {
  int blk = blockIdx.x;  // b*32 + h
  int b = blk >> 5, h = blk & 31;
  __shared__ u16 T[256][33];
  const float* xrow = x + ((size_t)b * 1024 + h * 32) * 256;
  int tid = threadIdx.x;
  for (int idx = tid; idx < 8192; idx += 256) {
    int w = idx >> 8, c = idx & 255;
    u16 v = f2bf(xrow[(size_t)w * 256 + c]);
    T[c][w] = v;
    xpad[((size_t)b * NPOS + (h + 1) * 34 + (w + 1)) * 256 + c] = v;
  }
  __syncthreads();
  int c = tid;
  unsigned int* dp = (unsigned int*)(xT + ((size_t)(b * 256 + c)) * 1024 + h * 32);
  const unsigned int* sp = (const unsigned int*)&T[c][0];
#pragma unroll
  for (int u = 0; u < 16; ++u) dp[u] = sp[u];
}

// weight transpose: src f32 [K][256] -> dst bf16 [256][K]
__global__ __launch_bounds__(256) void wtrans(
    const float* __restrict__ src, u16* __restrict__ dst, int K) {
  int k0 = blockIdx.x * 32;
  __shared__ u16 T[256][34];
  int tid = threadIdx.x;
  for (int idx = tid; idx < 8192; idx += 256) {
    int kr = idx >> 8, c = idx & 255;
    T[c][kr] = f2bf(src[(size_t)(k0 + kr) * 256 + c]);
  }
  __syncthreads();
  int c = tid;
  unsigned int* dp = (unsigned int*)(dst + (size_t)c * K + k0);
  const unsigned int* sp = (const unsigned int*)&T[c][0];
#pragma unroll
  for (int u = 0; u < 16; ++u) dp[u] = sp[u];
}

// ---------------------------------------------------------------------------
// Gbase[p,l] = sum_c x[p,c]*x[l,c] -> Gpad (spatially padded f32, zero border)
// ---------------------------------------------------------------------------
__global__ __launch_bounds__(256) void gram_base(
    const u16* __restrict__ xpad, float* __restrict__ Gpad) {
  const int b = blockIdx.z;
  const int m0 = blockIdx.x << 7;
  const int n0 = blockIdx.y << 7;
  const u16* xb = xpad + (size_t)b * NPOS * 256;
  __shared__ __align__(16) u16 As[128 * 64];
  __shared__ __align__(16) u16 Bs[128 * 64];
  const int tid = threadIdx.x;
  const int lane = tid & 63;
  const int wave = tid >> 6;
  const int wm = wave >> 1, wn = wave & 1;
  const int srow = lane >> 3;
  const int cswz = ((lane & 7) ^ srow) << 3;
  int pa[4], pb[4];
#pragma unroll
  for (int i = 0; i < 4; ++i) {
    pa[i] = posOf(m0 + wave * 32 + i * 8 + srow);
    pb[i] = posOf(n0 + wave * 32 + i * 8 + srow);
  }
  int aidx[4][2], bidx[4][2];
#pragma unroll
  for (int f = 0; f < 4; ++f)
#pragma unroll
    for (int ks = 0; ks < 2; ++ks) {
      int ra = wm * 64 + f * 16 + (lane & 15);
      int rb = wn * 64 + f * 16 + (lane & 15);
      int k16 = ks * 4 + (lane >> 4);
      aidx[f][ks] = ra * 64 + ((k16 ^ (ra & 7)) << 3);
      bidx[f][ks] = rb * 64 + ((k16 ^ (rb & 7)) << 3);
    }
  f32x4 acc[4][4] = {};
  for (int c0 = 0; c0 < 256; c0 += 64) {
    __syncthreads();
#pragma unroll
    for (int i = 0; i < 4; ++i) {
      gload16(xb + (size_t)pa[i] * 256 + c0 + cswz, &As[(wave * 32 + i * 8) * 64]);
      gload16(xb + (size_t)pb[i] * 256 + c0 + cswz, &Bs[(wave * 32 + i * 8) * 64]);
    }
    __syncthreads();
#pragma unroll
    for (int ks = 0; ks < 2; ++ks) {
      bf16x8 a[4], bb[4];
#pragma unroll
      for (int f = 0; f < 4; ++f) a[f] = *(const bf16x8*)(As + aidx[f][ks]);
#pragma unroll
      for (int f = 0; f < 4; ++f) bb[f] = *(const bf16x8*)(Bs + bidx[f][ks]);
#pragma unroll
      for (int mi = 0; mi < 4; ++mi)
#pragma unroll
        for (int ni = 0; ni < 4; ++ni)
          acc[mi][ni] = __builtin_amdgcn_mfma_f32_16x16x32_bf16(a[mi], bb[ni], acc[mi][ni], 0, 0, 0);
    }
  }
  float* Gb = Gpad + (size_t)b * GOFF;
  const int r0 = (lane >> 4) << 2;
  const int cb0 = n0 + wn * 64 + (lane & 15);
#pragma unroll
  for (int mi = 0; mi < 4; ++mi) {
    int row = m0 + wm * 64 + mi * 16 + r0;
    int rp = POS34(row);  // rows row..row+3 contiguous in pos-space
#pragma unroll
    for (int ni = 0; ni < 4; ++ni) {
      int cp = POS34(cb0 + ni * 16);
#pragma unroll
      for (int r = 0; r < 4; ++r)
        Gb[(size_t)(rp + r) * GSTR + cp] = acc[mi][ni][r];
    }
  }
}

// ---------------------------------------------------------------------------
// invn from 9-tap diagonal of Gpad; mm; ones tail
// ---------------------------------------------------------------------------
__global__ __launch_bounds__(256) void norm_mm(
    const float* __restrict__ Gpad, const float* __restrict__ mask,
    float* __restrict__ invn, float* __restrict__ mm, float* __restrict__ ones_out) {
  int idx = blockIdx.x * 256 + threadIdx.x;
  int b = idx >> 10, l = idx & 1023;
  const float* Gb = Gpad + (size_t)b * GOFF;
  size_t dbase = (size_t)POS34(l) * (GSTR + 1);
  float d = 0.f;
#pragma unroll
  for (int t = 0; t < 9; ++t) d += Gb[dbase + kDiagOff[t]];
  invn[idx] = 1.0f / fmaxf(sqrtf(d), 1e-4f);
  int lh = l >> 5, lw = l & 31;
  float s = 0.f;
  for (int dh = -1; dh <= 1; ++dh)
    for (int dw = -1; dw <= 1; ++dw) {
      int hh = lh + dh, wv = lw + dw;
      if (hh >= 0 && hh < 32 && wv >= 0 && wv < 32) s += mask[b * 1024 + hh * 32 + wv];
    }
  mm[idx] = ((s / 9.0f) == 1.0f) ? 1.0f : 0.0f;
  ones_out[idx] = 1.0f;
}

// ---------------------------------------------------------------------------
// Ylin[p+1][l+1] = invn[l] * sum_t Gpad[ppos+d_t][lpos+d_t]  (unconditional)
// ---------------------------------------------------------------------------
__global__ __launch_bounds__(256) void patch_norm_p(
    const float* __restrict__ Gpad, const float* __restrict__ invn,
    float* __restrict__ Ylin) {
  const int b = blockIdx.y;
  const int p0 = blockIdx.x << 2;
  const float* Gb = Gpad + (size_t)b * GOFF;
  float* Yb = Ylin + (size_t)b * YOFF;
  const int tid = threadIdx.x;
  const int l0 = tid << 2;
  const int lp0 = POS34(l0);
  const float4 iv = *(const float4*)(invn + (b << 10) + l0);
#pragma unroll
  for (int r = 0; r < 4; ++r) {
    int p = p0 + r;
    int base = POS34(p) * GSTR + lp0;
    float v[9][4];
#pragma unroll
    for (int t = 0; t < 9; ++t) {
      const float* q = Gb + (base + kDiagOff[t]);
      v[t][0] = q[0]; v[t][1] = q[1]; v[t][2] = q[2]; v[t][3] = q[3];
    }
    float s0 = 0.f, s1 = 0.f, s2 = 0.f, s3 = 0.f;
#pragma unroll
    for (int t = 0; t < 9; ++t) { s0 += v[t][0]; s1 += v[t][1]; s2 += v[t][2]; s3 += v[t][3]; }
    float* yw = Yb + (size_t)(p + 1) * YSTR + l0 + 1;
    yw[0] = s0 * iv.x; yw[1] = s1 * iv.y; yw[2] = s2 * iv.z; yw[3] = s3 * iv.w;
  }
}

// ---------------------------------------------------------------------------
// Fused diag-fuse + mask + softmax: reads Ylin (1-padded), writes A (f32,
// spatially padded Apad2 which aliases dead Gpad - borders already zero)
// ---------------------------------------------------------------------------
__device__ __forceinline__ float z1p(const float* __restrict__ Yb, int r, int c) {
  size_t a = (size_t)(r + 1) * YSTR + (c + 1);
  return Yb[a] + Yb[a - (YSTR + 1)] + Yb[a + (YSTR + 1)];
}

__global__ __launch_bounds__(256) void fuse_softmax(
    const float* __restrict__ Ylin, const float* __restrict__ mm,
    float* __restrict__ Apad2) {
  const int bi = blockIdx.x;
  const int b = bi >> 10, i = bi & 1023;
  const float* Yb = Ylin + (size_t)b * YOFF;
  __shared__ float smm[1024];
  __shared__ float red[256];
  const int tid = threadIdx.x;
  for (int t = tid; t < 1024; t += 256) smm[t] = mm[(b << 10) + t];
  __syncthreads();
  const int si = ((i & 31) << 5) | (i >> 5);
  const int rm = (si >= 1) ? ((((si - 1) & 31) << 5) | ((si - 1) >> 5)) : -1;
  const int rp = (si <= 1022) ? ((((si + 1) & 31) << 5) | ((si + 1) >> 5)) : -1;
  float logit[4];
  float lmax = -3.0e38f;
#pragma unroll
  for (int q = 0; q < 4; ++q) {
    int j = tid + (q << 8);
    int sj = ((j & 31) << 5) | (j >> 5);
    float S = z1p(Yb, i, j);
    if (rm >= 0 && sj >= 1) {
      int col = (((sj - 1) & 31) << 5) | ((sj - 1) >> 5);
      S += z1p(Yb, rm, col);
    }
    if (rp >= 0 && sj <= 1022) {
      int col = (((sj + 1) & 31) << 5) | ((sj + 1) >> 5);
      S += z1p(Yb, rp, col);
    }
    float lg = S * smm[j] * 10.0f;
    logit[q] = lg;
    lmax = fmaxf(lmax, lg);
  }
  red[tid] = lmax; __syncthreads();
  for (int off = 128; off > 0; off >>= 1) {
    if (tid < off) red[tid] = fmaxf(red[tid], red[tid + off]);
    __syncthreads();
  }
  float M = red[0];
  __syncthreads();
  float ex[4];
  float lsum = 0.f;
#pragma unroll
  for (int q = 0; q < 4; ++q) { ex[q] = expf(logit[q] - M); lsum += ex[q]; }
  red[tid] = lsum; __syncthreads();
  for (int off = 128; off > 0; off >>= 1) {
    if (tid < off) red[tid] += red[tid + off];
    __syncthreads();
  }
  float inv = 1.0f / red[0];
  float* Ap = Apad2 + (size_t)b * GOFF + (size_t)POS34(i) * GSTR;
#pragma unroll
  for (int q = 0; q < 4; ++q) {
    int j = tid + (q << 8);
    Ap[POS34(j)] = smm[j] * ex[q] * inv;
  }
}

// ---------------------------------------------------------------------------
// Afuse[q][l] (dense bf16) = sum_t Apad2[qpos-d_t][lpos-d_t]  (unconditional)
// ---------------------------------------------------------------------------
__global__ __launch_bounds__(256) void afuse_p(
    const float* __restrict__ Apad2, u16* __restrict__ Afuse) {
  const int b = blockIdx.y;
  const int q0 = blockIdx.x << 2;
  const float* Ab = Apad2 + (size_t)b * GOFF;
  u16* Fb = Afuse + ((size_t)b << 20);
  const int tid = threadIdx.x;
  const int l0 = tid << 2;
  const int lp0 = POS34(l0);
#pragma unroll
  for (int r = 0; r < 4; ++r) {
    int q = q0 + r;
    int base = POS34(q) * GSTR + lp0;
    float v[9][4];
#pragma unroll
    for (int t = 0; t < 9; ++t) {
      const float* p = Ab + (base - kDiagOff[t]);
      v[t][0] = p[0]; v[t][1] = p[1]; v[t][2] = p[2]; v[t][3] = p[3];
    }
    float s0 = 0.f, s1 = 0.f, s2 = 0.f, s3 = 0.f;
#pragma unroll
    for (int t = 0; t < 9; ++t) { s0 += v[t][0]; s1 += v[t][1]; s2 += v[t][2]; s3 += v[t][3]; }
    u16* fw = Fb + (size_t)q * 1024 + l0;
    fw[0] = f2bf(s0); fw[1] = f2bf(s1); fw[2] = f2bf(s2); fw[3] = f2bf(s3);
  }
}

// ---------------------------------------------------------------------------
// paste GEMM: ypad[q,c] = sum_l Afuse[q,l] * x[l,c]; M64 x N128, K=1024
// ---------------------------------------------------------------------------
__global__ __launch_bounds__(256) void paste_gemm(
    const u16* __restrict__ Afuse, const u16* __restrict__ xT, u16* __restrict__ ypad) {
  const int bm0 = blockIdx.x << 6;
  const int b = bm0 >> 10;
  const int q0 = bm0 & 1023;
  const int n0 = blockIdx.y << 7;
  const u16* Ab = Afuse + ((size_t)b << 20);
  const u16* xTb = xT + ((size_t)b << 18);
  __shared__ __align__(16) u16 As[64 * 64];
  __shared__ __align__(16) u16 Bs[128 * 64];
  const int tid = threadIdx.x;
  const int lane = tid & 63;
  const int wave = tid >> 6;
  const int wm = wave >> 1, wn = wave & 1;
  const int srow = lane >> 3;
  const int cswz = ((lane & 7) ^ srow) << 3;
  int aidx[2][2], bidx[4][2];
#pragma unroll
  for (int ks = 0; ks < 2; ++ks) {
    int k16 = ks * 4 + (lane >> 4);
#pragma unroll
    for (int f = 0; f < 2; ++f) {
      int ra = wm * 32 + f * 16 + (lane & 15);
      aidx[f][ks] = ra * 64 + ((k16 ^ (ra & 7)) << 3);
    }
#pragma unroll
    for (int f = 0; f < 4; ++f) {
      int rb = wn * 64 + f * 16 + (lane & 15);
      bidx[f][ks] = rb * 64 + ((k16 ^ (rb & 7)) << 3);
    }
  }
  f32x4 acc[2][4] = {};
  for (int l0 = 0; l0 < 1024; l0 += 64) {
    __syncthreads();
#pragma unroll
    for (int i = 0; i < 2; ++i) {
      int ar = wave * 16 + i * 8 + srow;
      gload16(Ab + (size_t)(q0 + ar) * 1024 + l0 + cswz, &As[ar * 64]);
    }
#pragma unroll
    for (int i = 0; i < 4; ++i) {
      int br = wave * 32 + i * 8 + srow;
      gload16(xTb + (size_t)(n0 + br) * 1024 + l0 + cswz, &Bs[br * 64]);
    }
    __syncthreads();
#pragma unroll
    for (int ks = 0; ks < 2; ++ks) {
      bf16x8 a[2], bb[4];
#pragma unroll
      for (int f = 0; f < 2; ++f) a[f] = *(const bf16x8*)(As + aidx[f][ks]);
#pragma unroll
      for (int f = 0; f < 4; ++f) bb[f] = *(const bf16x8*)(Bs + bidx[f][ks]);
#pragma unroll
      for (int mi = 0; mi < 2; ++mi)
#pragma unroll
        for (int ni = 0; ni < 4; ++ni)
          acc[mi][ni] = __builtin_amdgcn_mfma_f32_16x16x32_bf16(a[mi], bb[ni], acc[mi][ni], 0, 0, 0);
    }
  }
  u16* yb = ypad + (size_t)b * NPOS * 256;
  const int r0 = (lane >> 4) << 2;
#pragma unroll
  for (int mi = 0; mi < 2; ++mi) {
    int qb = q0 + wm * 32 + mi * 16 + r0;
#pragma unroll
    for (int ni = 0; ni < 4; ++ni) {
      int c = n0 + wn * 64 + ni * 16 + (lane & 15);
#pragma unroll
      for (int r = 0; r < 4; ++r)
        yb[(size_t)posOf(qb + r) * 256 + c] = f2bf(acc[mi][ni][r]);
    }
  }
}

// ---------------------------------------------------------------------------
// final fused: 3 convs + gating, M128 x N64, K = 9*512 (+512 center)
// ---------------------------------------------------------------------------
__global__ __launch_bounds__(256) void final_fused(
    const u16* __restrict__ ypad, const u16* __restrict__ xpad,
    const u16* __restrict__ w0T, const u16* __restrict__ w1T,
    const u16* __restrict__ w2T,
    const float* __restrict__ b0, const float* __restrict__ b1,
    const float* __restrict__ b2, float* __restrict__ out) {
  const int m0 = blockIdx.x << 7;
  const int b = m0 >> 10;
  const int q0 = m0 & 1023;
  const int n0 = blockIdx.y << 6;
  const u16* yb = ypad + (size_t)b * NPOS * 256;
  const u16* xb = xpad + (size_t)b * NPOS * 256;
  __shared__ __align__(16) u16 As[128 * 64];
  __shared__ __align__(16) u16 B0s[64 * 64];
  __shared__ __align__(16) u16 B1s[64 * 64];
  __shared__ __align__(16) u16 B2s[64 * 64];
  const int tid = threadIdx.x;
  const int lane = tid & 63;
  const int wave = tid >> 6;
  const int wm = wave >> 1, wn = wave & 1;
  const int srow = lane >> 3;
  const int cswz = ((lane & 7) ^ srow) << 3;
  int posA[4];
#pragma unroll
  for (int i = 0; i < 4; ++i) posA[i] = posOf(q0 + wave * 32 + i * 8 + srow);
  int aidx[4][2], bidx[2][2];
#pragma unroll
  for (int ks = 0; ks < 2; ++ks) {
    int k16 = ks * 4 + (lane >> 4);
#pragma unroll
    for (int f = 0; f < 4; ++f) {
      int ra = wm * 64 + f * 16 + (lane & 15);
      aidx[f][ks] = ra * 64 + ((k16 ^ (ra & 7)) << 3);
    }
#pragma unroll
    for (int f = 0; f < 2; ++f) {
      int rb = wn * 32 + f * 16 + (lane & 15);
      bidx[f][ks] = rb * 64 + ((k16 ^ (rb & 7)) << 3);
    }
  }
  f32x4 acc0[4][2] = {}, acc1[4][2] = {}, acc2[4][2] = {};
  for (int s = 0; s < 9; ++s) {
    const int dpos = (s / 3 - 1) * 34 + (s % 3 - 1);
    for (int c0 = 0; c0 < 512; c0 += 64) {
      const u16* base = (c0 < 256) ? yb : xb;
      const int coff = c0 & 255;
      __syncthreads();
#pragma unroll
      for (int i = 0; i < 4; ++i) {
        int ar = wave * 32 + i * 8 + srow;
        gload16(base + (size_t)(posA[i] + dpos) * 256 + coff + cswz, &As[ar * 64]);
      }
#pragma unroll
      for (int i = 0; i < 2; ++i) {
        int br = wave * 16 + i * 8 + srow;
        size_t krow = (size_t)(n0 + br) * 4608 + s * 512 + c0 + cswz;
        gload16(w0T + krow, &B0s[br * 64]);
        gload16(w2T + krow, &B2s[br * 64]);
      }
      if (s == 4) {
#pragma unroll
        for (int i = 0; i < 2; ++i) {
          int br = wave * 16 + i * 8 + srow;
          gload16(w1T + (size_t)(n0 + br) * 512 + c0 + cswz, &B1s[br * 64]);
        }
      }
      __syncthreads();
#pragma unroll
      for (int ks = 0; ks < 2; ++ks) {
        bf16x8 a[4], v0[2], v2[2];
#pragma unroll
        for (int f = 0; f < 4; ++f) a[f] = *(const bf16x8*)(As + aidx[f][ks]);
#pragma unroll
        for (int f = 0; f < 2; ++f) v0[f] = *(const bf16x8*)(B0s + bidx[f][ks]);
#pragma unroll
        for (int f = 0; f < 2; ++f) v2[f] = *(const bf16x8*)(B2s + bidx[f][ks]);
#pragma unroll
        for (int mi = 0; mi < 4; ++mi)
#pragma unroll
          for (int ni = 0; ni < 2; ++ni) {
            acc0[mi][ni] = __builtin_amdgcn_mfma_f32_16x16x32_bf16(a[mi], v0[ni], acc0[mi][ni], 0, 0, 0);
            acc2[mi][ni] = __builtin_amdgcn_mfma_f32_16x16x32_bf16(a[mi], v2[ni], acc2[mi][ni], 0, 0, 0);
          }
        if (s == 4) {
          bf16x8 v1[2];
#pragma unroll
          for (int f = 0; f < 2; ++f) v1[f] = *(const bf16x8*)(B1s + bidx[f][ks]);
#pragma unroll
          for (int mi = 0; mi < 4; ++mi)
#pragma unroll
            for (int ni = 0; ni < 2; ++ni)
              acc1[mi][ni] = __builtin_amdgcn_mfma_f32_16x16x32_bf16(a[mi], v1[ni], acc1[mi][ni], 0, 0, 0);
        }
      }
    }
  }
  const int r0 = (lane >> 4) << 2;
#pragma unroll
  for (int ni = 0; ni < 2; ++ni) {
    int co = n0 + wn * 32 + ni * 16 + (lane & 15);
    float q0b = b0[co], q1b = b1[co], q2b = b2[co];
#pragma unroll
    for (int mi = 0; mi < 4; ++mi) {
      int m = m0 + wm * 64 + mi * 16 + r0;
#pragma unroll
      for (int r = 0; r < 4; ++r) {
        float g1 = 1.f / (1.f + expf(-(acc1[mi][ni][r] + q1b)));
        float g2 = 1.f / (1.f + expf(-(acc2[mi][ni][r] + q2b)));
        out[(size_t)(m + r) * 256 + co] = 0.5f * (g1 + g2) * (acc0[mi][ni][r] + q0b);
      }
    }
  }
}

// ---------------------------------------------------------------------------

extern "C" void kernel_launch(void* const* d_in, const int* in_sizes, int n_in,
                              void* d_out, int out_size, void* d_ws, size_t ws_size,
                              hipStream_t stream) {
  const float* x = (const float*)d_in[0];
  const float* mask = (const float*)d_in[1];
  const float* conv_w = (const float*)d_in[2];
  const float* conv_b = (const float*)d_in[3];
  const float* conv1_w = (const float*)d_in[4];
  const float* conv1_b = (const float*)d_in[5];
  const float* conv2_w = (const float*)d_in[6];
  const float* conv2_b = (const float*)d_in[7];
  float* out = (float*)d_out;
  char* wsb = (char*)d_ws;

  // workspace layout (bytes)
  float* Gpad  = (float*)(wsb + 0);          // 42,910,720 (Apad2 aliases after)
  float* Apad2 = (float*)(wsb + 0);
  float* Ylin  = (float*)(wsb + 42910720);   // 33,882,624
  u16* Afuse   = (u16*)(wsb + 42910720);     // 16,777,216  (aliases dead Ylin)
  u16* xpad    = (u16*)(wsb + 76793344);     //  4,734,976
  u16* ypad    = (u16*)(wsb + 81528320);     //  4,734,976
  u16* xT      = (u16*)(wsb + 86263296);     //  4,194,304
  u16* w0T     = (u16*)(wsb + 90457600);     //  2,359,296
  u16* w2T     = (u16*)(wsb + 92816896);     //  2,359,296
  u16* w1T     = (u16*)(wsb + 95176192);     //    262,144
  float* invn  = (float*)(wsb + 95438336);
  float* mmb   = (float*)(wsb + 95471104);

  hipMemsetAsync(wsb, 0, 42910720, stream);            // Gpad (borders)
  hipMemsetAsync(wsb + 42910720, 0, 33882624, stream); // Ylin (borders)
  hipMemsetAsync(wsb + 76793344, 0, 9469952, stream);  // xpad + ypad borders

  cast_x<<<256, 256, 0, stream>>>(x, xpad, xT);
  wtrans<<<144, 256, 0, stream>>>(conv_w, w0T, 4608);
  wtrans<<<144, 256, 0, stream>>>(conv2_w, w2T, 4608);
  wtrans<<<16, 256, 0, stream>>>(conv1_w, w1T, 512);

  gram_base<<<dim3(8, 8, 8), 256, 0, stream>>>(xpad, Gpad);
  norm_mm<<<32, 256, 0, stream>>>(Gpad, mask, invn, mmb, out + 2097152);
  patch_norm_p<<<dim3(256, 8), 256, 0, stream>>>(Gpad, invn, Ylin);
  fuse_softmax<<<8192, 256, 0, stream>>>(Ylin, mmb, Apad2);
  afuse_p<<<dim3(256, 8), 256, 0, stream>>>(Apad2, Afuse);
  paste_gemm<<<dim3(128, 2), 256, 0, stream>>>(Afuse, xT, ypad);
  final_fused<<<dim3(64, 4), 256, 0, stream>>>(ypad, xpad, w0T, w1T, w2T,
                                               conv_b, conv1_b, conv2_b, out);
}

// Round 6
// 281.732 us; speedup vs baseline: 6.7716x; 1.0647x over previous
//
#include <hip/hip_runtime.h>
#include <math.h>

typedef unsigned short u16;
typedef __bf16 bf16x8 __attribute__((ext_vector_type(8)));
typedef float f32x4 __attribute__((ext_vector_type(4)));

#define NPOS 1156           // 34*34 padded positions
#define GSTR 1160           // Gpad/Apad2 row stride (f32 elems)
#define GOFF (GSTR * 1156)  // per-batch Gpad elems = 1340960
#define YSTR 1032           // Ylin row stride
#define YOFF (YSTR * 1026)  // per-batch Ylin elems = 1058832
#define POS34(p) ((((p) >> 5) + 1) * 34 + ((p) & 31) + 1)

__device__ __constant__ const int kDiagOff[9] = {
    -35 * (GSTR + 1), -34 * (GSTR + 1), -33 * (GSTR + 1),
    -1 * (GSTR + 1),  0,                1 * (GSTR + 1),
    33 * (GSTR + 1),  34 * (GSTR + 1),  35 * (GSTR + 1)};

__device__ __forceinline__ u16 f2bf(float f) {
  unsigned int u = __builtin_bit_cast(unsigned int, f);
  return (u16)((u + 0x7FFFu + ((u >> 16) & 1u)) >> 16);
}
__device__ __forceinline__ float bf2f(u16 v) {
  unsigned int u = ((unsigned int)v) << 16;
  return __builtin_bit_cast(float, u);
}
__device__ __forceinline__ void gload16(const void* g, void* l) {
  __builtin_amdgcn_global_load_lds(
      (const __attribute__((address_space(1))) void*)g,
      (__attribute__((address_space(3))) void*)l, 16, 0, 0);
}
__device__ __forceinline__ int posOf(int p) { return POS34(p); }

// ---------------------------------------------------------------------------
// cast x -> xpad [b][34][34][256] bf16 and xT [b][256][1024] bf16
// ---------------------------------------------------------------------------
__global__ __launch_bounds__(256) void cast_x(
    const float* __restrict__ x, u16* __restrict__ xpad, u16* __restrict__ xT) {
  int blk = blockIdx.x;  // b*32 + h
  int b = blk >> 5, h = blk & 31;
  __shared__ u16 T[256][33];
  const float* xrow = x + ((size_t)b * 1024 + h * 32) * 256;
  int tid = threadIdx.x;
  for (int idx = tid; idx < 8192; idx += 256) {
    int w = idx >> 8, c = idx & 255;
    u16 v = f2bf(xrow[(size_t)w * 256 + c]);
    T[c][w] = v;
    xpad[((size_t)b * NPOS + (h + 1) * 34 + (w + 1)) * 256 + c] = v;
  }
  __syncthreads();
  int c = tid;
  unsigned int* dp = (unsigned int*)(xT + ((size_t)(b * 256 + c)) * 1024 + h * 32);
  const unsigned int* sp = (const unsigned int*)&T[c][0];
#pragma unroll
  for (int u = 0; u < 16; ++u) dp[u] = sp[u];
}

// weight transpose: src f32 [K][256] -> dst bf16 [256][K]
__global__ __launch_bounds__(256) void wtrans(
    const float* __restrict__ src, u16* __restrict__ dst, int K) {
  int k0 = blockIdx.x * 32;
  __shared__ u16 T[256][34];
  int tid = threadIdx.x;
  for (int idx = tid; idx < 8192; idx += 256) {
    int kr = idx >> 8, c = idx & 255;
    T[c][kr] = f2bf(src[(size_t)(k0 + kr) * 256 + c]);
  }
  __syncthreads();
  int c = tid;
  unsigned int* dp = (unsigned int*)(dst + (size_t)c * K + k0);
  const unsigned int* sp = (const unsigned int*)&T[c][0];
#pragma unroll
  for (int u = 0; u < 16; ++u) dp[u] = sp[u];
}

// ---------------------------------------------------------------------------
// Gbase[p,l] = sum_c x[p,c]*x[l,c] -> Gpad (spatially padded f32, zero border)
// ---------------------------------------------------------------------------
__global__ __launch_bounds__(256) void gram_base(
    const u16* __restrict__ xpad, float* __restrict__ Gpad) {
  const int b = blockIdx.z;
  const int m0 = blockIdx.x << 7;
  const int n0 = blockIdx.y << 7;
  const u16* xb = xpad + (size_t)b * NPOS * 256;
  __shared__ __align__(16) u16 As[128 * 64];
  __shared__ __align__(16) u16 Bs[128 * 64];
  const int tid = threadIdx.x;
  const int lane = tid & 63;
  const int wave = tid >> 6;
  const int wm = wave >> 1, wn = wave & 1;
  const int srow = lane >> 3;
  const int cswz = ((lane & 7) ^ srow) << 3;
  int pa[4], pb[4];
#pragma unroll
  for (int i = 0; i < 4; ++i) {
    pa[i] = posOf(m0 + wave * 32 + i * 8 + srow);
    pb[i] = posOf(n0 + wave * 32 + i * 8 + srow);
  }
  int aidx[4][2], bidx[4][2];
#pragma unroll
  for (int f = 0; f < 4; ++f)
#pragma unroll
    for (int ks = 0; ks < 2; ++ks) {
      int ra = wm * 64 + f * 16 + (lane & 15);
      int rb = wn * 64 + f * 16 + (lane & 15);
      int k16 = ks * 4 + (lane >> 4);
      aidx[f][ks] = ra * 64 + ((k16 ^ (ra & 7)) << 3);
      bidx[f][ks] = rb * 64 + ((k16 ^ (rb & 7)) << 3);
    }
  f32x4 acc[4][4] = {};
  for (int c0 = 0; c0 < 256; c0 += 64) {
    __syncthreads();
#pragma unroll
    for (int i = 0; i < 4; ++i) {
      gload16(xb + (size_t)pa[i] * 256 + c0 + cswz, &As[(wave * 32 + i * 8) * 64]);
      gload16(xb + (size_t)pb[i] * 256 + c0 + cswz, &Bs[(wave * 32 + i * 8) * 64]);
    }
    __syncthreads();
#pragma unroll
    for (int ks = 0; ks < 2; ++ks) {
      bf16x8 a[4], bb[4];
#pragma unroll
      for (int f = 0; f < 4; ++f) a[f] = *(const bf16x8*)(As + aidx[f][ks]);
#pragma unroll
      for (int f = 0; f < 4; ++f) bb[f] = *(const bf16x8*)(Bs + bidx[f][ks]);
#pragma unroll
      for (int mi = 0; mi < 4; ++mi)
#pragma unroll
        for (int ni = 0; ni < 4; ++ni)
          acc[mi][ni] = __builtin_amdgcn_mfma_f32_16x16x32_bf16(a[mi], bb[ni], acc[mi][ni], 0, 0, 0);
    }
  }
  float* Gb = Gpad + (size_t)b * GOFF;
  const int r0 = (lane >> 4) << 2;
  const int cb0 = n0 + wn * 64 + (lane & 15);
#pragma unroll
  for (int mi = 0; mi < 4; ++mi) {
    int row = m0 + wm * 64 + mi * 16 + r0;
    int rp = POS34(row);  // rows row..row+3 contiguous in pos-space
#pragma unroll
    for (int ni = 0; ni < 4; ++ni) {
      int cp = POS34(cb0 + ni * 16);
#pragma unroll
      for (int r = 0; r < 4; ++r)
        Gb[(size_t)(rp + r) * GSTR + cp] = acc[mi][ni][r];
    }
  }
}

// ---------------------------------------------------------------------------
// invn from 9-tap diagonal of Gpad; mm; ones tail
// ---------------------------------------------------------------------------
__global__ __launch_bounds__(256) void norm_mm(
    const float* __restrict__ Gpad, const float* __restrict__ mask,
    float* __restrict__ invn, float* __restrict__ mm, float* __restrict__ ones_out) {
  int idx = blockIdx.x * 256 + threadIdx.x;
  int b = idx >> 10, l = idx & 1023;
  const float* Gb = Gpad + (size_t)b * GOFF;
  size_t dbase = (size_t)POS34(l) * (GSTR + 1);
  float d = 0.f;
#pragma unroll
  for (int t = 0; t < 9; ++t) d += Gb[dbase + kDiagOff[t]];
  invn[idx] = 1.0f / fmaxf(sqrtf(d), 1e-4f);
  int lh = l >> 5, lw = l & 31;
  float s = 0.f;
  for (int dh = -1; dh <= 1; ++dh)
    for (int dw = -1; dw <= 1; ++dw) {
      int hh = lh + dh, wv = lw + dw;
      if (hh >= 0 && hh < 32 && wv >= 0 && wv < 32) s += mask[b * 1024 + hh * 32 + wv];
    }
  mm[idx] = ((s / 9.0f) == 1.0f) ? 1.0f : 0.0f;
  ones_out[idx] = 1.0f;
}

// ---------------------------------------------------------------------------
// Ylin[p+1][l+1] = invn[l] * sum_t Gpad[ppos+d_t][lpos+d_t]  (unconditional)
// ---------------------------------------------------------------------------
__global__ __launch_bounds__(256) void patch_norm_p(
    const float* __restrict__ Gpad, const float* __restrict__ invn,
    float* __restrict__ Ylin) {
  const int b = blockIdx.y;
  const int p0 = blockIdx.x << 2;
  const float* Gb = Gpad + (size_t)b * GOFF;
  float* Yb = Ylin + (size_t)b * YOFF;
  const int tid = threadIdx.x;
  const int l0 = tid << 2;
  const int lp0 = POS34(l0);
  const float4 iv = *(const float4*)(invn + (b << 10) + l0);
#pragma unroll
  for (int r = 0; r < 4; ++r) {
    int p = p0 + r;
    int base = POS34(p) * GSTR + lp0;
    float v[9][4];
#pragma unroll
    for (int t = 0; t < 9; ++t) {
      const float* q = Gb + (base + kDiagOff[t]);
      v[t][0] = q[0]; v[t][1] = q[1]; v[t][2] = q[2]; v[t][3] = q[3];
    }
    float s0 = 0.f, s1 = 0.f, s2 = 0.f, s3 = 0.f;
#pragma unroll
    for (int t = 0; t < 9; ++t) { s0 += v[t][0]; s1 += v[t][1]; s2 += v[t][2]; s3 += v[t][3]; }
    float* yw = Yb + (size_t)(p + 1) * YSTR + l0 + 1;
    yw[0] = s0 * iv.x; yw[1] = s1 * iv.y; yw[2] = s2 * iv.z; yw[3] = s3 * iv.w;
  }
}

// ---------------------------------------------------------------------------
// Fused diag-fuse + mask + softmax: reads Ylin (1-padded), writes A (f32,
// spatially padded Apad2 which aliases dead Gpad - borders already zero)
// ---------------------------------------------------------------------------
__device__ __forceinline__ float z1p(const float* __restrict__ Yb, int r, int c) {
  size_t a = (size_t)(r + 1) * YSTR + (c + 1);
  return Yb[a] + Yb[a - (YSTR + 1)] + Yb[a + (YSTR + 1)];
}

__global__ __launch_bounds__(256) void fuse_softmax(
    const float* __restrict__ Ylin, const float* __restrict__ mm,
    float* __restrict__ Apad2) {
  const int bi = blockIdx.x;
  const int b = bi >> 10, i = bi & 1023;
  const float* Yb = Ylin + (size_t)b * YOFF;
  __shared__ float smm[1024];
  __shared__ float red[256];
  const int tid = threadIdx.x;
  for (int t = tid; t < 1024; t += 256) smm[t] = mm[(b << 10) + t];
  __syncthreads();
  const int si = ((i & 31) << 5) | (i >> 5);
  const int rm = (si >= 1) ? ((((si - 1) & 31) << 5) | ((si - 1) >> 5)) : -1;
  const int rp = (si <= 1022) ? ((((si + 1) & 31) << 5) | ((si + 1) >> 5)) : -1;
  float logit[4];
  float lmax = -3.0e38f;
#pragma unroll
  for (int q = 0; q < 4; ++q) {
    int j = tid + (q << 8);
    int sj = ((j & 31) << 5) | (j >> 5);
    float S = z1p(Yb, i, j);
    if (rm >= 0 && sj >= 1) {
      int col = (((sj - 1) & 31) << 5) | ((sj - 1) >> 5);
      S += z1p(Yb, rm, col);
    }
    if (rp >= 0 && sj <= 1022) {
      int col = (((sj + 1) & 31) << 5) | ((sj + 1) >> 5);
      S += z1p(Yb, rp, col);
    }
    float lg = S * smm[j] * 10.0f;
    logit[q] = lg;
    lmax = fmaxf(lmax, lg);
  }
  red[tid] = lmax; __syncthreads();
  for (int off = 128; off > 0; off >>= 1) {
    if (tid < off) red[tid] = fmaxf(red[tid], red[tid + off]);
    __syncthreads();
  }
  float M = red[0];
  __syncthreads();
  float ex[4];
  float lsum = 0.f;
#pragma unroll
  for (int q = 0; q < 4; ++q) { ex[q] = expf(logit[q] - M); lsum += ex[q]; }
  red[tid] = lsum; __syncthreads();
  for (int off = 128; off > 0; off >>= 1) {
    if (tid < off) red[tid] += red[tid + off];
    __syncthreads();
  }
  float inv = 1.0f / red[0];
  float* Ap = Apad2 + (size_t)b * GOFF + (size_t)POS34(i) * GSTR;
#pragma unroll
  for (int q = 0; q < 4; ++q) {
    int j = tid + (q << 8);
    Ap[POS34(j)] = smm[j] * ex[q] * inv;
  }
}

// ---------------------------------------------------------------------------
// Afuse[q][l] (dense bf16) = sum_t Apad2[qpos-d_t][lpos-d_t]  (unconditional)
// ---------------------------------------------------------------------------
__global__ __launch_bounds__(256) void afuse_p(
    const float* __restrict__ Apad2, u16* __restrict__ Afuse) {
  const int b = blockIdx.y;
  const int q0 = blockIdx.x << 2;
  const float* Ab = Apad2 + (size_t)b * GOFF;
  u16* Fb = Afuse + ((size_t)b << 20);
  const int tid = threadIdx.x;
  const int l0 = tid << 2;
  const int lp0 = POS34(l0);
#pragma unroll
  for (int r = 0; r < 4; ++r) {
    int q = q0 + r;
    int base = POS34(q) * GSTR + lp0;
    float v[9][4];
#pragma unroll
    for (int t = 0; t < 9; ++t) {
      const float* p = Ab + (base - kDiagOff[t]);
      v[t][0] = p[0]; v[t][1] = p[1]; v[t][2] = p[2]; v[t][3] = p[3];
    }
    float s0 = 0.f, s1 = 0.f, s2 = 0.f, s3 = 0.f;
#pragma unroll
    for (int t = 0; t < 9; ++t) { s0 += v[t][0]; s1 += v[t][1]; s2 += v[t][2]; s3 += v[t][3]; }
    u16* fw = Fb + (size_t)q * 1024 + l0;
    fw[0] = f2bf(s0); fw[1] = f2bf(s1); fw[2] = f2bf(s2); fw[3] = f2bf(s3);
  }
}

// ---------------------------------------------------------------------------
// paste GEMM: ypad[q,c] = sum_l Afuse[q,l] * x[l,c]; M64 x N64, K=1024
// 512 blocks -> 2 blocks/CU so staging drains of one block overlap MFMA of the other
// ---------------------------------------------------------------------------
__global__ __launch_bounds__(256) void paste_gemm(
    const u16* __restrict__ Afuse, const u16* __restrict__ xT, u16* __restrict__ ypad) {
  const int bm0 = blockIdx.x << 6;
  const int b = bm0 >> 10;
  const int q0 = bm0 & 1023;
  const int n0 = blockIdx.y << 6;
  const u16* Ab = Afuse + ((size_t)b << 20);
  const u16* xTb = xT + ((size_t)b << 18);
  __shared__ __align__(16) u16 As[64 * 64];
  __shared__ __align__(16) u16 Bs[64 * 64];
  const int tid = threadIdx.x;
  const int lane = tid & 63;
  const int wave = tid >> 6;
  const int wm = wave >> 1, wn = wave & 1;
  const int srow = lane >> 3;
  const int cswz = ((lane & 7) ^ srow) << 3;
  int aidx[2][2], bidx[2][2];
#pragma unroll
  for (int ks = 0; ks < 2; ++ks) {
    int k16 = ks * 4 + (lane >> 4);
#pragma unroll
    for (int f = 0; f < 2; ++f) {
      int ra = wm * 32 + f * 16 + (lane & 15);
      aidx[f][ks] = ra * 64 + ((k16 ^ (ra & 7)) << 3);
      int rb = wn * 32 + f * 16 + (lane & 15);
      bidx[f][ks] = rb * 64 + ((k16 ^ (rb & 7)) << 3);
    }
  }
  f32x4 acc[2][2] = {};
  for (int l0 = 0; l0 < 1024; l0 += 64) {
    __syncthreads();
#pragma unroll
    for (int i = 0; i < 2; ++i) {
      int ar = wave * 16 + i * 8 + srow;
      gload16(Ab + (size_t)(q0 + ar) * 1024 + l0 + cswz, &As[ar * 64]);
      gload16(xTb + (size_t)(n0 + ar) * 1024 + l0 + cswz, &Bs[ar * 64]);
    }
    __syncthreads();
#pragma unroll
    for (int ks = 0; ks < 2; ++ks) {
      bf16x8 a[2], bb[2];
#pragma unroll
      for (int f = 0; f < 2; ++f) a[f] = *(const bf16x8*)(As + aidx[f][ks]);
#pragma unroll
      for (int f = 0; f < 2; ++f) bb[f] = *(const bf16x8*)(Bs + bidx[f][ks]);
#pragma unroll
      for (int mi = 0; mi < 2; ++mi)
#pragma unroll
        for (int ni = 0; ni < 2; ++ni)
          acc[mi][ni] = __builtin_amdgcn_mfma_f32_16x16x32_bf16(a[mi], bb[ni], acc[mi][ni], 0, 0, 0);
    }
  }
  u16* yb = ypad + (size_t)b * NPOS * 256;
  const int r0 = (lane >> 4) << 2;
#pragma unroll
  for (int mi = 0; mi < 2; ++mi) {
    int qb = q0 + wm * 32 + mi * 16 + r0;
#pragma unroll
    for (int ni = 0; ni < 2; ++ni) {
      int c = n0 + wn * 32 + ni * 16 + (lane & 15);
#pragma unroll
      for (int r = 0; r < 4; ++r)
        yb[(size_t)posOf(qb + r) * 256 + c] = f2bf(acc[mi][ni][r]);
    }
  }
}

// ---------------------------------------------------------------------------
// final fused: 3 convs + gating, M64 x N64 (512 blocks -> 2/CU), K = 9*512
// ---------------------------------------------------------------------------
__global__ __launch_bounds__(256) void final_fused(
    const u16* __restrict__ ypad, const u16* __restrict__ xpad,
    const u16* __restrict__ w0T, const u16* __restrict__ w1T,
    const u16* __restrict__ w2T,
    const float* __restrict__ b0, const float* __restrict__ b1,
    const float* __restrict__ b2, float* __restrict__ out) {
  const int m0 = blockIdx.x << 6;
  const int b = m0 >> 10;
  const int q0 = m0 & 1023;
  const int n0 = blockIdx.y << 6;
  const u16* yb = ypad + (size_t)b * NPOS * 256;
  const u16* xb = xpad + (size_t)b * NPOS * 256;
  __shared__ __align__(16) u16 As[64 * 64];
  __shared__ __align__(16) u16 B0s[64 * 64];
  __shared__ __align__(16) u16 B1s[64 * 64];
  __shared__ __align__(16) u16 B2s[64 * 64];
  const int tid = threadIdx.x;
  const int lane = tid & 63;
  const int wave = tid >> 6;
  const int wm = wave >> 1, wn = wave & 1;
  const int srow = lane >> 3;
  const int cswz = ((lane & 7) ^ srow) << 3;
  int posA[2];
#pragma unroll
  for (int i = 0; i < 2; ++i) posA[i] = posOf(q0 + wave * 16 + i * 8 + srow);
  int aidx[2][2], bidx[2][2];
#pragma unroll
  for (int ks = 0; ks < 2; ++ks) {
    int k16 = ks * 4 + (lane >> 4);
#pragma unroll
    for (int f = 0; f < 2; ++f) {
      int ra = wm * 32 + f * 16 + (lane & 15);
      aidx[f][ks] = ra * 64 + ((k16 ^ (ra & 7)) << 3);
      int rb = wn * 32 + f * 16 + (lane & 15);
      bidx[f][ks] = rb * 64 + ((k16 ^ (rb & 7)) << 3);
    }
  }
  f32x4 acc0[2][2] = {}, acc1[2][2] = {}, acc2[2][2] = {};
  for (int s = 0; s < 9; ++s) {
    const int dpos = (s / 3 - 1) * 34 + (s % 3 - 1);
    for (int c0 = 0; c0 < 512; c0 += 64) {
      const u16* base = (c0 < 256) ? yb : xb;
      const int coff = c0 & 255;
      __syncthreads();
#pragma unroll
      for (int i = 0; i < 2; ++i) {
        int ar = wave * 16 + i * 8 + srow;
        gload16(base + (size_t)(posA[i] + dpos) * 256 + coff + cswz, &As[ar * 64]);
        size_t krow = (size_t)(n0 + ar) * 4608 + s * 512 + c0 + cswz;
        gload16(w0T + krow, &B0s[ar * 64]);
        gload16(w2T + krow, &B2s[ar * 64]);
        if (s == 4)
          gload16(w1T + (size_t)(n0 + ar) * 512 + c0 + cswz, &B1s[ar * 64]);
      }
      __syncthreads();
#pragma unroll
      for (int ks = 0; ks < 2; ++ks) {
        bf16x8 a[2], v0[2], v2[2];
#pragma unroll
        for (int f = 0; f < 2; ++f) a[f] = *(const bf16x8*)(As + aidx[f][ks]);
#pragma unroll
        for (int f = 0; f < 2; ++f) v0[f] = *(const bf16x8*)(B0s + bidx[f][ks]);
#pragma unroll
        for (int f = 0; f < 2; ++f) v2[f] = *(const bf16x8*)(B2s + bidx[f][ks]);
#pragma unroll
        for (int mi = 0; mi < 2; ++mi)
#pragma unroll
          for (int ni = 0; ni < 2; ++ni) {
            acc0[mi][ni] = __builtin_amdgcn_mfma_f32_16x16x32_bf16(a[mi], v0[ni], acc0[mi][ni], 0, 0, 0);
            acc2[mi][ni] = __builtin_amdgcn_mfma_f32_16x16x32_bf16(a[mi], v2[ni], acc2[mi][ni], 0, 0, 0);
          }
        if (s == 4) {
          bf16x8 v1[2];
#pragma unroll
          for (int f = 0; f < 2; ++f) v1[f] = *(const bf16x8*)(B1s + bidx[f][ks]);
#pragma unroll
          for (int mi = 0; mi < 2; ++mi)
#pragma unroll
            for (int ni = 0; ni < 2; ++ni)
              acc1[mi][ni] = __builtin_amdgcn_mfma_f32_16x16x32_bf16(a[mi], v1[ni], acc1[mi][ni], 0, 0, 0);
        }
      }
    }
  }
  const int r0 = (lane >> 4) << 2;
#pragma unroll
  for (int ni = 0; ni < 2; ++ni) {
    int co = n0 + wn * 32 + ni * 16 + (lane & 15);
    float q0b = b0[co], q1b = b1[co], q2b = b2[co];
#pragma unroll
    for (int mi = 0; mi < 2; ++mi) {
      int m = m0 + wm * 32 + mi * 16 + r0;
#pragma unroll
      for (int r = 0; r < 4; ++r) {
        float g1 = 1.f / (1.f + expf(-(acc1[mi][ni][r] + q1b)));
        float g2 = 1.f / (1.f + expf(-(acc2[mi][ni][r] + q2b)));
        out[(size_t)(m + r) * 256 + co] = 0.5f * (g1 + g2) * (acc0[mi][ni][r] + q0b);
      }
    }
  }
}

// ---------------------------------------------------------------------------

extern "C" void kernel_launch(void* const* d_in, const int* in_sizes, int n_in,
                              void* d_out, int out_size, void* d_ws, size_t ws_size,
                              hipStream_t stream) {
  const float* x = (const float*)d_in[0];
  const float* mask = (const float*)d_in[1];
  const float* conv_w = (const float*)d_in[2];
  const float* conv_b = (const float*)d_in[3];
  const float* conv1_w = (const float*)d_in[4];
  const float* conv1_b = (const float*)d_in[5];
  const float* conv2_w = (const float*)d_in[6];
  const float* conv2_b = (const float*)d_in[7];
  float* out = (float*)d_out;
  char* wsb = (char*)d_ws;

  // workspace layout (bytes)
  float* Gpad  = (float*)(wsb + 0);          // 42,910,720 (Apad2 aliases after)
  float* Apad2 = (float*)(wsb + 0);
  float* Ylin  = (float*)(wsb + 42910720);   // 33,882,624
  u16* Afuse   = (u16*)(wsb + 42910720);     // 16,777,216  (aliases dead Ylin)
  u16* xpad    = (u16*)(wsb + 76793344);     //  4,734,976
  u16* ypad    = (u16*)(wsb + 81528320);     //  4,734,976
  u16* xT      = (u16*)(wsb + 86263296);     //  4,194,304
  u16* w0T     = (u16*)(wsb + 90457600);     //  2,359,296
  u16* w2T     = (u16*)(wsb + 92816896);     //  2,359,296
  u16* w1T     = (u16*)(wsb + 95176192);     //    262,144
  float* invn  = (float*)(wsb + 95438336);
  float* mmb   = (float*)(wsb + 95471104);

  hipMemsetAsync(wsb, 0, 76793344, stream);            // Gpad + Ylin borders
  hipMemsetAsync(wsb + 76793344, 0, 9469952, stream);  // xpad + ypad borders

  cast_x<<<256, 256, 0, stream>>>(x, xpad, xT);
  wtrans<<<144, 256, 0, stream>>>(conv_w, w0T, 4608);
  wtrans<<<144, 256, 0, stream>>>(conv2_w, w2T, 4608);
  wtrans<<<16, 256, 0, stream>>>(conv1_w, w1T, 512);

  gram_base<<<dim3(8, 8, 8), 256, 0, stream>>>(xpad, Gpad);
  norm_mm<<<32, 256, 0, stream>>>(Gpad, mask, invn, mmb, out + 2097152);
  patch_norm_p<<<dim3(256, 8), 256, 0, stream>>>(Gpad, invn, Ylin);
  fuse_softmax<<<8192, 256, 0, stream>>>(Ylin, mmb, Apad2);
  afuse_p<<<dim3(256, 8), 256, 0, stream>>>(Apad2, Afuse);
  paste_gemm<<<dim3(128, 4), 256, 0, stream>>>(Afuse, xT, ypad);
  final_fused<<<dim3(128, 4), 256, 0, stream>>>(ypad, xpad, w0T, w1T, w2T,
                                                conv_b, conv1_b, conv2_b, out);
}